// Round 11
// baseline (2764.785 us; speedup 1.0000x reference)
//
#include <hip/hip_runtime.h>
#include <cstdint>

#define D_MODELC 256
#define N_LAYERSC 4
#define BATCHC 64
#define SEQC 900
#define NCH 10
#define CT 90
#define SUB 45
#define LN_EPSF 1e-5f
#define LOG2E 1.44269504088896f

typedef __bf16 bf16x8 __attribute__((ext_vector_type(8)));
typedef __bf16 bf16x4 __attribute__((ext_vector_type(4)));
typedef float floatx4 __attribute__((ext_vector_type(4)));

#if defined(__has_builtin)
#if __has_builtin(__builtin_amdgcn_exp2f)
#define EXP2F __builtin_amdgcn_exp2f
#endif
#endif
#ifndef EXP2F
#define EXP2F exp2f
#endif

__device__ inline float sp(float v) { return (v > 20.f) ? v : log1pf(__expf(v)); }
__device__ inline float silu(float v) { return v / (1.f + __expf(-v)); }

// ---------------- weight transpose + cvt: W (L,K,N) -> Wb (L,N,K) bf16
__global__ void wprep(const float* __restrict__ W, __bf16* __restrict__ Wb,
                      int K, int N, int kshift) {
  int l = blockIdx.y;
  int idx = blockIdx.x * 256 + threadIdx.x;
  if (idx >= N * K) return;
  int n = idx >> kshift, k = idx & (K - 1);
  Wb[(size_t)l * N * K + idx] = (__bf16)W[(size_t)l * K * N + (size_t)k * N + n];
}

// ---------------- embed -> split bf16 x
__global__ void embed_kernel(const int* __restrict__ grid,
                             const float* __restrict__ cemb,
                             const float* __restrict__ pemb,
                             __bf16* __restrict__ xh, __bf16* __restrict__ xl) {
  int row = blockIdx.x;
  int c = threadIdx.x;
  int s = row % SEQC;
  int g = grid[row];
  float v = cemb[g * D_MODELC + c] + pemb[s * D_MODELC + c];
  size_t o = (size_t)row * D_MODELC + c;
  __bf16 hh = (__bf16)v;
  xh[o] = hh;
  xl[o] = (__bf16)(v - (float)hh);
}

// ---------------- bf16 MFMA GEMM: C = A(MxK) * W^T(NxK) + bias
// 128x128 tile, 4 waves (2x2), BK=32. M % 128 == 0, K % 32 == 0.
// Grid: x = col tiles, y = row tiles.
// Epilogue for wide outputs goes through LDS -> full-line 16B stores
// (avoids L2 write-allocate HBM fetches that doubled traffic).
// mode 1: bf16 out Cb, softplus on cols < 16 (x-proj delta) — direct stores
// mode 2: in-proj: tile col-block < 512 -> Cb = v ; >= 512 -> Cg = silu(v)
// mode 3: bf16 out Cb plain (out-proj)
#define GLDA 44     // staging row stride (88 B): conflict-free ds_read
#define CLDA 136    // epilogue row stride (272 B = 16B-aligned)
__global__ __launch_bounds__(256) void gemm_bf16(
    const __bf16* __restrict__ A, const __bf16* __restrict__ W,
    const float* __restrict__ bias,
    __bf16* __restrict__ Cb, __bf16* __restrict__ Cg,
    int M, int N, int K, int mode) {
  __shared__ __attribute__((aligned(16))) __bf16 smem[128 * CLDA]; // 34816 B
  __bf16* As = smem;                 // 128*44 elems
  __bf16* Bs = smem + 128 * GLDA;    // 128*44 elems (total 22528 B <= 34816)
  __bf16* Cs = smem;                 // epilogue reuse

  int tid = threadIdx.x, lane = tid & 63, w = tid >> 6;
  int bm = blockIdx.y * 128, bn = blockIdx.x * 128;
  int wm = (w >> 1) * 64, wn = (w & 1) * 64;
  int lm = lane & 15, kq = lane >> 4;

  floatx4 acc[4][4];
  floatx4 zero = {0.f, 0.f, 0.f, 0.f};
  #pragma unroll
  for (int i = 0; i < 4; ++i)
    #pragma unroll
    for (int j = 0; j < 4; ++j) acc[i][j] = zero;

  int r0 = tid >> 1;          // 0..127
  int kb = (tid & 1) * 16;    // 0 / 16

  for (int k0 = 0; k0 < K; k0 += 32) {
    __syncthreads();
    {
      size_t aoff = (size_t)(bm + r0) * K + k0 + kb;
      *(bf16x8*)&As[r0 * GLDA + kb]     = *(const bf16x8*)&A[aoff];
      *(bf16x8*)&As[r0 * GLDA + kb + 8] = *(const bf16x8*)&A[aoff + 8];
      int nr = bn + r0;
      if (nr < N) {
        size_t boff = (size_t)nr * K + k0 + kb;
        *(bf16x8*)&Bs[r0 * GLDA + kb]     = *(const bf16x8*)&W[boff];
        *(bf16x8*)&Bs[r0 * GLDA + kb + 8] = *(const bf16x8*)&W[boff + 8];
      } else {
        uint4 zu = make_uint4(0, 0, 0, 0);
        *(uint4*)&Bs[r0 * GLDA + kb] = zu;
        *(uint4*)&Bs[r0 * GLDA + kb + 8] = zu;
      }
    }
    __syncthreads();
    bf16x8 fa[4], fb[4];
    #pragma unroll
    for (int mt = 0; mt < 4; ++mt)
      fa[mt] = *(const bf16x8*)&As[(wm + mt * 16 + lm) * GLDA + kq * 8];
    #pragma unroll
    for (int nt = 0; nt < 4; ++nt)
      fb[nt] = *(const bf16x8*)&Bs[(wn + nt * 16 + lm) * GLDA + kq * 8];
    #pragma unroll
    for (int mt = 0; mt < 4; ++mt)
      #pragma unroll
      for (int nt = 0; nt < 4; ++nt)
        acc[mt][nt] = __builtin_amdgcn_mfma_f32_16x16x32_bf16(fa[mt], fb[nt], acc[mt][nt], 0, 0, 0);
  }

  if (mode == 1) {
    // direct scalar stores (N=32, tiny write volume)
    #pragma unroll
    for (int mt = 0; mt < 4; ++mt)
      #pragma unroll
      for (int nt = 0; nt < 4; ++nt) {
        int col = bn + wn + nt * 16 + lm;
        if (col >= N) continue;
        float bz = bias[col];
        #pragma unroll
        for (int i = 0; i < 4; ++i) {
          int row = bm + wm + mt * 16 + kq * 4 + i;
          float v = acc[mt][nt][i] + bz;
          if (col < 16) v = sp(v);           // softplus(delta)
          Cb[(size_t)row * N + col] = (__bf16)v;
        }
      }
    return;
  }

  // ---- LDS-staged epilogue (modes 2, 3): full-line coalesced writes
  __syncthreads();   // all frag ds_reads done before Cs overwrite
  bool gatehalf = (mode == 2) && (bn >= 512);
  #pragma unroll
  for (int mt = 0; mt < 4; ++mt)
    #pragma unroll
    for (int nt = 0; nt < 4; ++nt) {
      int coll = wn + nt * 16 + lm;
      float bz = bias[bn + coll];
      #pragma unroll
      for (int i = 0; i < 4; ++i) {
        int rowl = wm + mt * 16 + kq * 4 + i;
        float v = acc[mt][nt][i] + bz;
        if (gatehalf) v = silu(v);
        Cs[rowl * CLDA + coll] = (__bf16)v;
      }
    }
  __syncthreads();
  {
    __bf16* dst;
    int ldc;
    if (mode == 2) {
      ldc = 512;
      dst = gatehalf ? (Cg + (bn - 512)) : (Cb + bn);
    } else {
      ldc = N;
      dst = Cb + bn;
    }
    #pragma unroll
    for (int i = 0; i < 8; ++i) {
      int idx = tid + i * 256;
      int r = idx >> 4, cg = (idx & 15) * 8;
      *(bf16x8*)&dst[(size_t)(bm + r) * ldc + cg] =
          *(const bf16x8*)&Cs[r * CLDA + cg];
    }
  }
}

// ---------------- depthwise causal conv (k=4) + SiLU, bf16 in/out, 8 ch/thread
__global__ void conv_silu(const __bf16* __restrict__ xs,
                          const float* __restrict__ cw,
                          const float* __restrict__ cb,
                          __bf16* __restrict__ xc, int total) {
  int idx = blockIdx.x * 256 + threadIdx.x;   // < R*64
  if (idx >= total) return;
  int d8 = (idx & 63) * 8;
  int bt = idx >> 6;
  int t = bt % SEQC;
  const __bf16* base = xs + (size_t)(bt - t) * 512 + d8;
  float wv[8][4];
  #pragma unroll
  for (int e = 0; e < 8; ++e) {
    float4 wq = *(const float4*)&cw[(d8 + e) * 4];
    wv[e][0] = wq.x; wv[e][1] = wq.y; wv[e][2] = wq.z; wv[e][3] = wq.w;
  }
  float4 b0 = *(const float4*)&cb[d8];
  float4 b1 = *(const float4*)&cb[d8 + 4];
  float acc[8] = {b0.x, b0.y, b0.z, b0.w, b1.x, b1.y, b1.z, b1.w};
  #pragma unroll
  for (int j = 0; j < 4; ++j) {
    int ts = t - 3 + j;
    if (ts >= 0) {
      bf16x8 v = *(const bf16x8*)&base[(size_t)ts * 512];
      #pragma unroll
      for (int e = 0; e < 8; ++e) acc[e] = fmaf(wv[e][j], (float)v[e], acc[e]);
    }
  }
  bf16x8 o;
  #pragma unroll
  for (int e = 0; e < 8; ++e) o[e] = (__bf16)silu(acc[e]);
  *(bf16x8*)&xc[(size_t)bt * 512 + d8] = o;
}

// ---------------- scan phase 1: per-chunk local scan (h=0) -> hend, P (bf16)
__global__ __launch_bounds__(256, 4) void scan_phase1(
    const __bf16* __restrict__ ssm, const float* __restrict__ A_log,
    const __bf16* __restrict__ xc,
    __bf16* __restrict__ hend, __bf16* __restrict__ Pp) {
  __shared__ float sb[SUB * 32];
  __shared__ __bf16 xsb[SUB * 256];
  int b = blockIdx.x, half = blockIdx.y, c = blockIdx.z;
  int tid = threadIdx.x;
  int dg0 = half * 256;
  int d = dg0 + tid;
  float a2[16];
  #pragma unroll
  for (int n = 0; n < 16; ++n) a2[n] = -__expf(A_log[d * 16 + n]) * LOG2E;
  float h[16] = {}, S[16] = {};
  size_t rowbase = (size_t)b * SEQC + c * CT;

  for (int sub = 0; sub < 2; ++sub) {
    int ts0 = sub * SUB;
    __syncthreads();
    for (int i = tid; i < SUB * 8; i += 256) {
      int tt = i >> 3, n4 = (i & 7) * 4;
      bf16x4 v = *(const bf16x4*)&ssm[(rowbase + ts0 + tt) * 32 + n4];
      float4 f = {(float)v[0], (float)v[1], (float)v[2], (float)v[3]};
      *(float4*)&sb[tt * 32 + n4] = f;
    }
    for (int i = tid; i < SUB * 64; i += 256) {
      int tt = i >> 6, j4 = (i & 63) * 4;
      *(bf16x4*)&xsb[tt * 256 + j4] =
          *(const bf16x4*)&xc[(rowbase + ts0 + tt) * 512 + dg0 + j4];
    }
    __syncthreads();
    for (int tt = 0; tt < SUB; ++tt) {
      const float4* dv = (const float4*)&sb[tt * 32];
      float4 d0 = dv[0], d1 = dv[1], d2 = dv[2], d3 = dv[3];
      float4 e0 = dv[4], e1 = dv[5], e2 = dv[6], e3 = dv[7];
      float del[16] = {d0.x, d0.y, d0.z, d0.w, d1.x, d1.y, d1.z, d1.w,
                       d2.x, d2.y, d2.z, d2.w, d3.x, d3.y, d3.z, d3.w};
      float Bv[16]  = {e0.x, e0.y, e0.z, e0.w, e1.x, e1.y, e1.z, e1.w,
                       e2.x, e2.y, e2.z, e2.w, e3.x, e3.y, e3.z, e3.w};
      float xv = (float)xsb[tt * 256 + tid];
      #pragma unroll
      for (int n = 0; n < 16; ++n) {
        S[n] += del[n];
        float e = EXP2F(a2[n] * del[n]);
        h[n] = fmaf(h[n], e, xv * Bv[n]);
      }
    }
  }
  size_t base = ((size_t)(b * NCH + c) * 512 + d) * 16;
  bf16x8 h0, h1, p0, p1;
  #pragma unroll
  for (int n = 0; n < 8; ++n) {
    h0[n] = (__bf16)h[n]; h1[n] = (__bf16)h[n + 8];
    p0[n] = (__bf16)EXP2F(a2[n] * S[n]);
    p1[n] = (__bf16)EXP2F(a2[n + 8] * S[n + 8]);
  }
  *(bf16x8*)&hend[base] = h0; *(bf16x8*)&hend[base + 8] = h1;
  *(bf16x8*)&Pp[base] = p0;   *(bf16x8*)&Pp[base + 8] = p1;
}

// ---------------- scan phase 2: sequential carry composition (hend -> hin in place)
__global__ __launch_bounds__(64) void scan_combine(
    __bf16* __restrict__ hend, const __bf16* __restrict__ Pp) {
  int b = blockIdx.x;
  int d = blockIdx.y * 64 + threadIdx.x;
  float hp[16] = {};
  for (int c = 0; c < NCH; ++c) {
    size_t base = ((size_t)(b * NCH + c) * 512 + d) * 16;
    bf16x8 he0 = *(const bf16x8*)&hend[base];
    bf16x8 he1 = *(const bf16x8*)&hend[base + 8];
    bf16x8 pp0 = *(const bf16x8*)&Pp[base];
    bf16x8 pp1 = *(const bf16x8*)&Pp[base + 8];
    bf16x8 o0, o1;
    #pragma unroll
    for (int n = 0; n < 8; ++n) {
      o0[n] = (__bf16)hp[n]; o1[n] = (__bf16)hp[n + 8];
      hp[n]     = fmaf((float)pp0[n], hp[n],     (float)he0[n]);
      hp[n + 8] = fmaf((float)pp1[n], hp[n + 8], (float)he1[n]);
    }
    *(bf16x8*)&hend[base] = o0; *(bf16x8*)&hend[base + 8] = o1;
  }
}

// ---------------- scan phase 3: local scan with carry, y, gate -> yc bf16
__global__ __launch_bounds__(256, 4) void scan_phase3(
    const __bf16* __restrict__ ssm, const float* __restrict__ A_log,
    const float* __restrict__ Dp, const __bf16* __restrict__ xc,
    const __bf16* __restrict__ gate, const __bf16* __restrict__ hin,
    __bf16* __restrict__ yc) {
  __shared__ float sb[SUB * 32];
  __shared__ __bf16 xsb[SUB * 256];
  int b = blockIdx.x, half = blockIdx.y, c = blockIdx.z;
  int tid = threadIdx.x;
  int dg0 = half * 256;
  int d = dg0 + tid;
  float a2[16];
  #pragma unroll
  for (int n = 0; n < 16; ++n) a2[n] = -__expf(A_log[d * 16 + n]) * LOG2E;
  float Dv = Dp[d];
  float h[16];
  {
    size_t base = ((size_t)(b * NCH + c) * 512 + d) * 16;
    bf16x8 h0 = *(const bf16x8*)&hin[base];
    bf16x8 h1 = *(const bf16x8*)&hin[base + 8];
    #pragma unroll
    for (int n = 0; n < 8; ++n) { h[n] = (float)h0[n]; h[n + 8] = (float)h1[n]; }
  }
  size_t rowbase = (size_t)b * SEQC + c * CT;

  for (int sub = 0; sub < 2; ++sub) {
    int ts0 = sub * SUB;
    __syncthreads();
    for (int i = tid; i < SUB * 8; i += 256) {
      int tt = i >> 3, n4 = (i & 7) * 4;
      bf16x4 v = *(const bf16x4*)&ssm[(rowbase + ts0 + tt) * 32 + n4];
      float4 f = {(float)v[0], (float)v[1], (float)v[2], (float)v[3]};
      *(float4*)&sb[tt * 32 + n4] = f;
    }
    for (int i = tid; i < SUB * 64; i += 256) {
      int tt = i >> 6, j4 = (i & 63) * 4;
      *(bf16x4*)&xsb[tt * 256 + j4] =
          *(const bf16x4*)&xc[(rowbase + ts0 + tt) * 512 + dg0 + j4];
    }
    __syncthreads();
    for (int tt = 0; tt < SUB; ++tt) {
      const float4* dv = (const float4*)&sb[tt * 32];
      float4 d0 = dv[0], d1 = dv[1], d2 = dv[2], d3 = dv[3];
      float4 e0 = dv[4], e1 = dv[5], e2 = dv[6], e3 = dv[7];
      float del[16] = {d0.x, d0.y, d0.z, d0.w, d1.x, d1.y, d1.z, d1.w,
                       d2.x, d2.y, d2.z, d2.w, d3.x, d3.y, d3.z, d3.w};
      float Bv[16]  = {e0.x, e0.y, e0.z, e0.w, e1.x, e1.y, e1.z, e1.w,
                       e2.x, e2.y, e2.z, e2.w, e3.x, e3.y, e3.z, e3.w};
      float xv = (float)xsb[tt * 256 + tid];
      float y0 = 0.f, y1 = 0.f, y2 = 0.f, y3 = 0.f;
      #pragma unroll
      for (int n = 0; n < 4; ++n) {
        float e = EXP2F(a2[n] * del[n]);
        h[n] = fmaf(h[n], e, xv * Bv[n]);
        y0 = fmaf(h[n], Bv[n], y0);
      }
      #pragma unroll
      for (int n = 4; n < 8; ++n) {
        float e = EXP2F(a2[n] * del[n]);
        h[n] = fmaf(h[n], e, xv * Bv[n]);
        y1 = fmaf(h[n], Bv[n], y1);
      }
      #pragma unroll
      for (int n = 8; n < 12; ++n) {
        float e = EXP2F(a2[n] * del[n]);
        h[n] = fmaf(h[n], e, xv * Bv[n]);
        y2 = fmaf(h[n], Bv[n], y2);
      }
      #pragma unroll
      for (int n = 12; n < 16; ++n) {
        float e = EXP2F(a2[n] * del[n]);
        h[n] = fmaf(h[n], e, xv * Bv[n]);
        y3 = fmaf(h[n], Bv[n], y3);
      }
      xsb[tt * 256 + tid] = (__bf16)fmaf(Dv, xv, (y0 + y1) + (y2 + y3));
    }
    __syncthreads();
    for (int i = tid; i < SUB * 64; i += 256) {
      int tt = i >> 6, j4 = (i & 63) * 4;
      size_t o = (rowbase + ts0 + tt) * 512 + dg0 + j4;
      bf16x4 y4 = *(const bf16x4*)&xsb[tt * 256 + j4];
      bf16x4 g4 = *(const bf16x4*)&gate[o];
      bf16x4 r;
      #pragma unroll
      for (int e = 0; e < 4; ++e) r[e] = (__bf16)((float)y4[e] * (float)g4[e]);
      *(bf16x4*)&yc[o] = r;
    }
  }
}

// ---------------- x = LayerNorm(reconstruct(xh,xl) + ob_bf16), re-split; 4 rows/block
__global__ __launch_bounds__(256) void add_ln(
    __bf16* __restrict__ xh, __bf16* __restrict__ xl,
    const __bf16* __restrict__ ob,
    const float* __restrict__ g, const float* __restrict__ bb) {
  int lane = threadIdx.x & 63;
  size_t base = ((size_t)blockIdx.x * 4 + (threadIdx.x >> 6)) * 256;
  bf16x4 h4 = *(const bf16x4*)&xh[base + lane * 4];
  bf16x4 l4 = *(const bf16x4*)&xl[base + lane * 4];
  bf16x4 o4 = *(const bf16x4*)&ob[base + lane * 4];
  float v[4];
  #pragma unroll
  for (int i = 0; i < 4; ++i) v[i] = (float)h4[i] + (float)l4[i] + (float)o4[i];
  float s = v[0] + v[1] + v[2] + v[3];
  #pragma unroll
  for (int off = 32; off > 0; off >>= 1) s += __shfl_down(s, off);
  float mu = __shfl(s, 0) * (1.f / 256.f);
  float var = 0.f;
  #pragma unroll
  for (int i = 0; i < 4; ++i) { float dd = v[i] - mu; var = fmaf(dd, dd, var); }
  #pragma unroll
  for (int off = 32; off > 0; off >>= 1) var += __shfl_down(var, off);
  float r = rsqrtf(__shfl(var, 0) * (1.f / 256.f) + LN_EPSF);
  float4 gv = *(const float4*)&g[lane * 4];
  float4 bv = *(const float4*)&bb[lane * 4];
  float gg[4] = {gv.x, gv.y, gv.z, gv.w};
  float bbv[4] = {bv.x, bv.y, bv.z, bv.w};
  bf16x4 hq, lq;
  #pragma unroll
  for (int i = 0; i < 4; ++i) {
    float o = (v[i] - mu) * r * gg[i] + bbv[i];
    __bf16 hh = (__bf16)o;
    hq[i] = hh;
    lq[i] = (__bf16)(o - (float)hh);
  }
  *(bf16x4*)&xh[base + lane * 4] = hq;
  *(bf16x4*)&xl[base + lane * 4] = lq;
}

// ---------------- fin[b][256] = reconstruct(x) at t=899
__global__ void extract_final(const __bf16* __restrict__ xh,
                              const __bf16* __restrict__ xl,
                              float* __restrict__ fin) {
  int b = blockIdx.x;
  int c = threadIdx.x;
  size_t o = ((size_t)b * SEQC + (SEQC - 1)) * D_MODELC + c;
  fin[(size_t)b * 256 + c] = (float)xh[o] + (float)xl[o];
}

// ---------------- final heads
__global__ __launch_bounds__(128) void heads_kernel(
    const float* __restrict__ fin,
    const float* __restrict__ cnt1_w, const float* __restrict__ cnt1_b,
    const float* __restrict__ cnt2_w, const float* __restrict__ cnt2_b,
    const float* __restrict__ col1_w, const float* __restrict__ col1_b,
    const float* __restrict__ col2_w, const float* __restrict__ col2_b,
    float* __restrict__ out) {
  int b = blockIdx.x;
  int tid = threadIdx.x;
  __shared__ float f[256];
  __shared__ float hc[128];
  __shared__ float hl[128];
  f[tid] = fin[b * 256 + tid];
  f[tid + 128] = fin[b * 256 + tid + 128];
  __syncthreads();
  float s1 = cnt1_b[tid], s2 = col1_b[tid];
  for (int c = 0; c < 256; ++c) {
    float v = f[c];
    s1 = fmaf(v, cnt1_w[c * 128 + tid], s1);
    s2 = fmaf(v, col1_w[c * 128 + tid], s2);
  }
  hc[tid] = fmaxf(s1, 0.f);
  hl[tid] = fmaxf(s2, 0.f);
  __syncthreads();
  if (tid == 0) {
    float t = cnt2_b[0];
    for (int j = 0; j < 128; ++j) t = fmaf(hc[j], cnt2_w[j], t);
    out[b] = fmaxf(t, 0.f);
  }
  if (tid < 10) {
    float t = col2_b[tid];
    for (int j = 0; j < 128; ++j) t = fmaf(hl[j], col2_w[j * 10 + tid], t);
    out[64 + b * 10 + tid] = fmaxf(t, 0.f);
  }
}

extern "C" void kernel_launch(void* const* d_in, const int* in_sizes, int n_in,
                              void* d_out, int out_size, void* d_ws, size_t ws_size,
                              hipStream_t stream) {
  const int*   grid   = (const int*)d_in[0];
  const float* cemb   = (const float*)d_in[1];
  const float* pemb   = (const float*)d_in[2];
  const float* in_w   = (const float*)d_in[3];
  const float* in_b   = (const float*)d_in[4];
  const float* conv_w = (const float*)d_in[5];
  const float* conv_b = (const float*)d_in[6];
  const float* xproj_w= (const float*)d_in[7];
  const float* xproj_b= (const float*)d_in[8];
  const float* A_log  = (const float*)d_in[9];
  const float* Dp     = (const float*)d_in[10];
  const float* out_w  = (const float*)d_in[11];
  const float* out_b  = (const float*)d_in[12];
  const float* ln_g   = (const float*)d_in[13];
  const float* ln_b   = (const float*)d_in[14];
  const float* cnt1_w = (const float*)d_in[15];
  const float* cnt1_b = (const float*)d_in[16];
  const float* cnt2_w = (const float*)d_in[17];
  const float* cnt2_b = (const float*)d_in[18];
  const float* col1_w = (const float*)d_in[19];
  const float* col1_b = (const float*)d_in[20];
  const float* col2_w = (const float*)d_in[21];
  const float* col2_b = (const float*)d_in[22];

  const int R = BATCHC * SEQC;  // 57600
  float* ws = (float*)d_ws;
  size_t off = 0;
  auto alloc = [&](size_t fl) { float* p = ws + off; off += (fl + 63) & ~(size_t)63; return p; };

  float*  fin   = alloc((size_t)BATCHC * 256);
  __bf16* wi    = (__bf16*)alloc((size_t)N_LAYERSC * 1024 * 256 / 2);
  __bf16* wx    = (__bf16*)alloc((size_t)N_LAYERSC * 32 * 512 / 2);
  __bf16* wo    = (__bf16*)alloc((size_t)N_LAYERSC * 256 * 512 / 2);
  __bf16* xh    = (__bf16*)alloc((size_t)R * 256 / 2);
  __bf16* xl    = (__bf16*)alloc((size_t)R * 256 / 2);
  __bf16* xsyc  = (__bf16*)alloc((size_t)R * 512 / 2);   // xs then yc
  float*  gateob= alloc((size_t)R * 512 / 2);            // gate bf16, then ob bf16
  __bf16* xc    = (__bf16*)alloc((size_t)R * 512 / 2);
  __bf16* ssm   = (__bf16*)alloc((size_t)R * 32 / 2);
  __bf16* hend  = (__bf16*)alloc((size_t)BATCHC * NCH * 512 * 16 / 2);
  __bf16* Pp    = (__bf16*)alloc((size_t)BATCHC * NCH * 512 * 16 / 2);
  __bf16* gate  = (__bf16*)gateob;
  __bf16* obb   = (__bf16*)gateob;   // out-proj result (gate dead after phase3)

  // weight prep (once per call)
  wprep<<<dim3(1024, N_LAYERSC), 256, 0, stream>>>(in_w, wi, 256, 1024, 8);
  wprep<<<dim3(64, N_LAYERSC), 256, 0, stream>>>(xproj_w, wx, 512, 32, 9);
  wprep<<<dim3(512, N_LAYERSC), 256, 0, stream>>>(out_w, wo, 512, 256, 9);

  embed_kernel<<<R, 256, 0, stream>>>(grid, cemb, pemb, xh, xl);

  for (int l = 0; l < N_LAYERSC; ++l) {
    // in-proj: xs (bf16) + gate = silu(res) (bf16)
    gemm_bf16<<<dim3(8, R / 128), 256, 0, stream>>>(
        xh, wi + (size_t)l * 1024 * 256, in_b + l * 1024,
        xsyc, gate, R, 1024, 256, 2);
    conv_silu<<<(R * 64 + 255) / 256, 256, 0, stream>>>(
        xsyc, conv_w + (size_t)l * 512 * 4, conv_b + l * 512, xc, R * 64);
    // x-proj: ssm bf16, softplus fused on delta cols
    gemm_bf16<<<dim3(1, R / 128), 256, 0, stream>>>(
        xc, wx + (size_t)l * 32 * 512, xproj_b + l * 32,
        ssm, nullptr, R, 32, 512, 1);
    scan_phase1<<<dim3(BATCHC, 2, NCH), 256, 0, stream>>>(
        ssm, A_log + (size_t)l * 512 * 16, xc, hend, Pp);
    scan_combine<<<dim3(BATCHC, 8), 64, 0, stream>>>(hend, Pp);
    scan_phase3<<<dim3(BATCHC, 2, NCH), 256, 0, stream>>>(
        ssm, A_log + (size_t)l * 512 * 16, Dp + l * 512, xc, gate, hend, xsyc);
    // out-proj: ob bf16 (overwrites gate region — gate dead after phase3)
    gemm_bf16<<<dim3(2, R / 128), 256, 0, stream>>>(
        xsyc, wo + (size_t)l * 256 * 512, out_b + l * 256,
        obb, nullptr, R, 256, 512, 3);
    add_ln<<<R / 4, 256, 0, stream>>>(xh, xl, obb, ln_g, ln_b);
  }

  extract_final<<<BATCHC, 256, 0, stream>>>(xh, xl, fin);
  heads_kernel<<<BATCHC, 128, 0, stream>>>(
      fin, cnt1_w, cnt1_b, cnt2_w, cnt2_b, col1_w, col1_b, col2_w, col2_b,
      (float*)d_out);
}

// Round 12
// 2324.186 us; speedup vs baseline: 1.1896x; 1.1896x over previous
//
#include <hip/hip_runtime.h>
#include <cstdint>

#define D_MODELC 256
#define N_LAYERSC 4
#define BATCHC 64
#define SEQC 900
#define NCH 10
#define CT 90
#define SUB 45
#define LN_EPSF 1e-5f
#define LOG2E 1.44269504088896f

typedef __bf16 bf16x8 __attribute__((ext_vector_type(8)));
typedef __bf16 bf16x4 __attribute__((ext_vector_type(4)));
typedef float floatx4 __attribute__((ext_vector_type(4)));

#if defined(__has_builtin)
#if __has_builtin(__builtin_amdgcn_exp2f)
#define EXP2F __builtin_amdgcn_exp2f
#endif
#endif
#ifndef EXP2F
#define EXP2F exp2f
#endif

__device__ inline float sp(float v) { return (v > 20.f) ? v : log1pf(__expf(v)); }
__device__ inline float silu(float v) { return v / (1.f + __expf(-v)); }

// ---------------- weight transpose + cvt: W (L,K,N) -> Wb (L,N,K) bf16
__global__ void wprep(const float* __restrict__ W, __bf16* __restrict__ Wb,
                      int K, int N, int kshift) {
  int l = blockIdx.y;
  int idx = blockIdx.x * 256 + threadIdx.x;
  if (idx >= N * K) return;
  int n = idx >> kshift, k = idx & (K - 1);
  Wb[(size_t)l * N * K + idx] = (__bf16)W[(size_t)l * K * N + (size_t)k * N + n];
}

// ---------------- embed -> split bf16 x
__global__ void embed_kernel(const int* __restrict__ grid,
                             const float* __restrict__ cemb,
                             const float* __restrict__ pemb,
                             __bf16* __restrict__ xh, __bf16* __restrict__ xl) {
  int row = blockIdx.x;
  int c = threadIdx.x;
  int s = row % SEQC;
  int g = grid[row];
  float v = cemb[g * D_MODELC + c] + pemb[s * D_MODELC + c];
  size_t o = (size_t)row * D_MODELC + c;
  __bf16 hh = (__bf16)v;
  xh[o] = hh;
  xl[o] = (__bf16)(v - (float)hh);
}

// ---------------- bf16 MFMA GEMM: C = A(MxK) * W^T(NxK) + bias
// 128x128 tile, 4 waves (2x2), BK=32, single-buffer (proven fastest r7/r8).
// M % 128 == 0, K % 32 == 0. Grid: x = col tiles, y = row tiles.
// mode 1: bf16 out Cb, softplus on cols < 16 (x-proj delta)
// mode 2: in-proj: col<512 -> Cb = v ; col>=512 -> Cg = silu(v)
// mode 3: bf16 out Cb plain (out-proj)
#define GLDA 44   // 88 B row stride — measured conflict-free (r11: 4.6e5)
__global__ __launch_bounds__(256) void gemm_bf16(
    const __bf16* __restrict__ A, const __bf16* __restrict__ W,
    const float* __restrict__ bias,
    __bf16* __restrict__ Cb, __bf16* __restrict__ Cg,
    int M, int N, int K, int mode) {
  __shared__ __attribute__((aligned(16))) __bf16 As[128 * GLDA];
  __shared__ __attribute__((aligned(16))) __bf16 Bs[128 * GLDA];
  int tid = threadIdx.x, lane = tid & 63, w = tid >> 6;
  int bm = blockIdx.y * 128, bn = blockIdx.x * 128;
  int wm = (w >> 1) * 64, wn = (w & 1) * 64;
  int lm = lane & 15, kq = lane >> 4;
  bool wactive = (bn + wn < N);   // x-proj (N=32): waves past N skip MFMA

  floatx4 acc[4][4];
  floatx4 zero = {0.f, 0.f, 0.f, 0.f};
  #pragma unroll
  for (int i = 0; i < 4; ++i)
    #pragma unroll
    for (int j = 0; j < 4; ++j) acc[i][j] = zero;

  int r0 = tid >> 1;          // 0..127
  int kb = (tid & 1) * 16;    // 0 / 16

  for (int k0 = 0; k0 < K; k0 += 32) {
    __syncthreads();
    {
      size_t aoff = (size_t)(bm + r0) * K + k0 + kb;
      *(bf16x8*)&As[r0 * GLDA + kb]     = *(const bf16x8*)&A[aoff];
      *(bf16x8*)&As[r0 * GLDA + kb + 8] = *(const bf16x8*)&A[aoff + 8];
      int nr = bn + r0;
      if (nr < N) {
        size_t boff = (size_t)nr * K + k0 + kb;
        *(bf16x8*)&Bs[r0 * GLDA + kb]     = *(const bf16x8*)&W[boff];
        *(bf16x8*)&Bs[r0 * GLDA + kb + 8] = *(const bf16x8*)&W[boff + 8];
      } else {
        uint4 zu = make_uint4(0, 0, 0, 0);
        *(uint4*)&Bs[r0 * GLDA + kb] = zu;
        *(uint4*)&Bs[r0 * GLDA + kb + 8] = zu;
      }
    }
    __syncthreads();
    if (wactive) {
      bf16x8 fa[4], fb[4];
      #pragma unroll
      for (int mt = 0; mt < 4; ++mt)
        fa[mt] = *(const bf16x8*)&As[(wm + mt * 16 + lm) * GLDA + kq * 8];
      #pragma unroll
      for (int nt = 0; nt < 4; ++nt)
        if (bn + wn + nt * 16 < N)
          fb[nt] = *(const bf16x8*)&Bs[(wn + nt * 16 + lm) * GLDA + kq * 8];
      #pragma unroll
      for (int mt = 0; mt < 4; ++mt)
        #pragma unroll
        for (int nt = 0; nt < 4; ++nt)
          if (bn + wn + nt * 16 < N)
            acc[mt][nt] = __builtin_amdgcn_mfma_f32_16x16x32_bf16(fa[mt], fb[nt], acc[mt][nt], 0, 0, 0);
    }
  }

  if (!wactive) return;
  #pragma unroll
  for (int mt = 0; mt < 4; ++mt)
    #pragma unroll
    for (int nt = 0; nt < 4; ++nt) {
      int col = bn + wn + nt * 16 + lm;
      if (col >= N) continue;
      float bz = bias[col];
      #pragma unroll
      for (int i = 0; i < 4; ++i) {
        int row = bm + wm + mt * 16 + kq * 4 + i;
        float v = acc[mt][nt][i] + bz;
        if (mode == 1) {
          if (col < 16) v = sp(v);           // softplus(delta) once here
          Cb[(size_t)row * N + col] = (__bf16)v;
        } else if (mode == 2) {
          if (col < 512) Cb[(size_t)row * 512 + col] = (__bf16)v;
          else           Cg[(size_t)row * 512 + col - 512] = (__bf16)silu(v);
        } else {
          Cb[(size_t)row * N + col] = (__bf16)v;
        }
      }
    }
}

// ---------------- depthwise causal conv (k=4) + SiLU, bf16 in/out, 8 ch/thread
__global__ void conv_silu(const __bf16* __restrict__ xs,
                          const float* __restrict__ cw,
                          const float* __restrict__ cb,
                          __bf16* __restrict__ xc, int total) {
  int idx = blockIdx.x * 256 + threadIdx.x;   // < R*64
  if (idx >= total) return;
  int d8 = (idx & 63) * 8;
  int bt = idx >> 6;
  int t = bt % SEQC;
  const __bf16* base = xs + (size_t)(bt - t) * 512 + d8;
  float wv[8][4];
  #pragma unroll
  for (int e = 0; e < 8; ++e) {
    float4 wq = *(const float4*)&cw[(d8 + e) * 4];
    wv[e][0] = wq.x; wv[e][1] = wq.y; wv[e][2] = wq.z; wv[e][3] = wq.w;
  }
  float4 b0 = *(const float4*)&cb[d8];
  float4 b1 = *(const float4*)&cb[d8 + 4];
  float acc[8] = {b0.x, b0.y, b0.z, b0.w, b1.x, b1.y, b1.z, b1.w};
  #pragma unroll
  for (int j = 0; j < 4; ++j) {
    int ts = t - 3 + j;
    if (ts >= 0) {
      bf16x8 v = *(const bf16x8*)&base[(size_t)ts * 512];
      #pragma unroll
      for (int e = 0; e < 8; ++e) acc[e] = fmaf(wv[e][j], (float)v[e], acc[e]);
    }
  }
  bf16x8 o;
  #pragma unroll
  for (int e = 0; e < 8; ++e) o[e] = (__bf16)silu(acc[e]);
  *(bf16x8*)&xc[(size_t)bt * 512 + d8] = o;
}

// ---------------- scan phase 1: per-chunk local scan (h=0) -> hend, P (bf16)
__global__ __launch_bounds__(256, 4) void scan_phase1(
    const __bf16* __restrict__ ssm, const float* __restrict__ A_log,
    const __bf16* __restrict__ xc,
    __bf16* __restrict__ hend, __bf16* __restrict__ Pp) {
  __shared__ float sb[SUB * 32];
  __shared__ __bf16 xsb[SUB * 256];
  int b = blockIdx.x, half = blockIdx.y, c = blockIdx.z;
  int tid = threadIdx.x;
  int dg0 = half * 256;
  int d = dg0 + tid;
  float a2[16];
  #pragma unroll
  for (int n = 0; n < 16; ++n) a2[n] = -__expf(A_log[d * 16 + n]) * LOG2E;
  float h[16] = {}, S[16] = {};
  size_t rowbase = (size_t)b * SEQC + c * CT;

  for (int sub = 0; sub < 2; ++sub) {
    int ts0 = sub * SUB;
    __syncthreads();
    for (int i = tid; i < SUB * 8; i += 256) {
      int tt = i >> 3, n4 = (i & 7) * 4;
      bf16x4 v = *(const bf16x4*)&ssm[(rowbase + ts0 + tt) * 32 + n4];
      float4 f = {(float)v[0], (float)v[1], (float)v[2], (float)v[3]};
      *(float4*)&sb[tt * 32 + n4] = f;
    }
    for (int i = tid; i < SUB * 64; i += 256) {
      int tt = i >> 6, j4 = (i & 63) * 4;
      *(bf16x4*)&xsb[tt * 256 + j4] =
          *(const bf16x4*)&xc[(rowbase + ts0 + tt) * 512 + dg0 + j4];
    }
    __syncthreads();
    for (int tt = 0; tt < SUB; ++tt) {
      const float4* dv = (const float4*)&sb[tt * 32];
      float4 d0 = dv[0], d1 = dv[1], d2 = dv[2], d3 = dv[3];
      float4 e0 = dv[4], e1 = dv[5], e2 = dv[6], e3 = dv[7];
      float del[16] = {d0.x, d0.y, d0.z, d0.w, d1.x, d1.y, d1.z, d1.w,
                       d2.x, d2.y, d2.z, d2.w, d3.x, d3.y, d3.z, d3.w};
      float Bv[16]  = {e0.x, e0.y, e0.z, e0.w, e1.x, e1.y, e1.z, e1.w,
                       e2.x, e2.y, e2.z, e2.w, e3.x, e3.y, e3.z, e3.w};
      float xv = (float)xsb[tt * 256 + tid];
      #pragma unroll
      for (int n = 0; n < 16; ++n) {
        S[n] += del[n];
        float e = EXP2F(a2[n] * del[n]);
        h[n] = fmaf(h[n], e, xv * Bv[n]);
      }
    }
  }
  size_t base = ((size_t)(b * NCH + c) * 512 + d) * 16;
  bf16x8 h0, h1, p0, p1;
  #pragma unroll
  for (int n = 0; n < 8; ++n) {
    h0[n] = (__bf16)h[n]; h1[n] = (__bf16)h[n + 8];
    p0[n] = (__bf16)EXP2F(a2[n] * S[n]);
    p1[n] = (__bf16)EXP2F(a2[n + 8] * S[n + 8]);
  }
  *(bf16x8*)&hend[base] = h0; *(bf16x8*)&hend[base + 8] = h1;
  *(bf16x8*)&Pp[base] = p0;   *(bf16x8*)&Pp[base + 8] = p1;
}

// ---------------- scan phase 2: sequential carry composition (hend -> hin in place)
__global__ __launch_bounds__(64) void scan_combine(
    __bf16* __restrict__ hend, const __bf16* __restrict__ Pp) {
  int b = blockIdx.x;
  int d = blockIdx.y * 64 + threadIdx.x;
  float hp[16] = {};
  for (int c = 0; c < NCH; ++c) {
    size_t base = ((size_t)(b * NCH + c) * 512 + d) * 16;
    bf16x8 he0 = *(const bf16x8*)&hend[base];
    bf16x8 he1 = *(const bf16x8*)&hend[base + 8];
    bf16x8 pp0 = *(const bf16x8*)&Pp[base];
    bf16x8 pp1 = *(const bf16x8*)&Pp[base + 8];
    bf16x8 o0, o1;
    #pragma unroll
    for (int n = 0; n < 8; ++n) {
      o0[n] = (__bf16)hp[n]; o1[n] = (__bf16)hp[n + 8];
      hp[n]     = fmaf((float)pp0[n], hp[n],     (float)he0[n]);
      hp[n + 8] = fmaf((float)pp1[n], hp[n + 8], (float)he1[n]);
    }
    *(bf16x8*)&hend[base] = o0; *(bf16x8*)&hend[base + 8] = o1;
  }
}

// ---------------- scan phase 3: local scan with carry, y, gate -> yc bf16
__global__ __launch_bounds__(256, 4) void scan_phase3(
    const __bf16* __restrict__ ssm, const float* __restrict__ A_log,
    const float* __restrict__ Dp, const __bf16* __restrict__ xc,
    const __bf16* __restrict__ gate, const __bf16* __restrict__ hin,
    __bf16* __restrict__ yc) {
  __shared__ float sb[SUB * 32];
  __shared__ __bf16 xsb[SUB * 256];
  int b = blockIdx.x, half = blockIdx.y, c = blockIdx.z;
  int tid = threadIdx.x;
  int dg0 = half * 256;
  int d = dg0 + tid;
  float a2[16];
  #pragma unroll
  for (int n = 0; n < 16; ++n) a2[n] = -__expf(A_log[d * 16 + n]) * LOG2E;
  float Dv = Dp[d];
  float h[16];
  {
    size_t base = ((size_t)(b * NCH + c) * 512 + d) * 16;
    bf16x8 h0 = *(const bf16x8*)&hin[base];
    bf16x8 h1 = *(const bf16x8*)&hin[base + 8];
    #pragma unroll
    for (int n = 0; n < 8; ++n) { h[n] = (float)h0[n]; h[n + 8] = (float)h1[n]; }
  }
  size_t rowbase = (size_t)b * SEQC + c * CT;

  for (int sub = 0; sub < 2; ++sub) {
    int ts0 = sub * SUB;
    __syncthreads();
    for (int i = tid; i < SUB * 8; i += 256) {
      int tt = i >> 3, n4 = (i & 7) * 4;
      bf16x4 v = *(const bf16x4*)&ssm[(rowbase + ts0 + tt) * 32 + n4];
      float4 f = {(float)v[0], (float)v[1], (float)v[2], (float)v[3]};
      *(float4*)&sb[tt * 32 + n4] = f;
    }
    for (int i = tid; i < SUB * 64; i += 256) {
      int tt = i >> 6, j4 = (i & 63) * 4;
      *(bf16x4*)&xsb[tt * 256 + j4] =
          *(const bf16x4*)&xc[(rowbase + ts0 + tt) * 512 + dg0 + j4];
    }
    __syncthreads();
    for (int tt = 0; tt < SUB; ++tt) {
      const float4* dv = (const float4*)&sb[tt * 32];
      float4 d0 = dv[0], d1 = dv[1], d2 = dv[2], d3 = dv[3];
      float4 e0 = dv[4], e1 = dv[5], e2 = dv[6], e3 = dv[7];
      float del[16] = {d0.x, d0.y, d0.z, d0.w, d1.x, d1.y, d1.z, d1.w,
                       d2.x, d2.y, d2.z, d2.w, d3.x, d3.y, d3.z, d3.w};
      float Bv[16]  = {e0.x, e0.y, e0.z, e0.w, e1.x, e1.y, e1.z, e1.w,
                       e2.x, e2.y, e2.z, e2.w, e3.x, e3.y, e3.z, e3.w};
      float xv = (float)xsb[tt * 256 + tid];
      float y0 = 0.f, y1 = 0.f, y2 = 0.f, y3 = 0.f;
      #pragma unroll
      for (int n = 0; n < 4; ++n) {
        float e = EXP2F(a2[n] * del[n]);
        h[n] = fmaf(h[n], e, xv * Bv[n]);
        y0 = fmaf(h[n], Bv[n], y0);
      }
      #pragma unroll
      for (int n = 4; n < 8; ++n) {
        float e = EXP2F(a2[n] * del[n]);
        h[n] = fmaf(h[n], e, xv * Bv[n]);
        y1 = fmaf(h[n], Bv[n], y1);
      }
      #pragma unroll
      for (int n = 8; n < 12; ++n) {
        float e = EXP2F(a2[n] * del[n]);
        h[n] = fmaf(h[n], e, xv * Bv[n]);
        y2 = fmaf(h[n], Bv[n], y2);
      }
      #pragma unroll
      for (int n = 12; n < 16; ++n) {
        float e = EXP2F(a2[n] * del[n]);
        h[n] = fmaf(h[n], e, xv * Bv[n]);
        y3 = fmaf(h[n], Bv[n], y3);
      }
      xsb[tt * 256 + tid] = (__bf16)fmaf(Dv, xv, (y0 + y1) + (y2 + y3));
    }
    __syncthreads();
    for (int i = tid; i < SUB * 64; i += 256) {
      int tt = i >> 6, j4 = (i & 63) * 4;
      size_t o = (rowbase + ts0 + tt) * 512 + dg0 + j4;
      bf16x4 y4 = *(const bf16x4*)&xsb[tt * 256 + j4];
      bf16x4 g4 = *(const bf16x4*)&gate[o];
      bf16x4 r;
      #pragma unroll
      for (int e = 0; e < 4; ++e) r[e] = (__bf16)((float)y4[e] * (float)g4[e]);
      *(bf16x4*)&yc[o] = r;
    }
  }
}

// ---------------- x = LayerNorm(reconstruct(xh,xl) + ob_bf16), re-split; 4 rows/block
__global__ __launch_bounds__(256) void add_ln(
    __bf16* __restrict__ xh, __bf16* __restrict__ xl,
    const __bf16* __restrict__ ob,
    const float* __restrict__ g, const float* __restrict__ bb) {
  int lane = threadIdx.x & 63;
  size_t base = ((size_t)blockIdx.x * 4 + (threadIdx.x >> 6)) * 256;
  bf16x4 h4 = *(const bf16x4*)&xh[base + lane * 4];
  bf16x4 l4 = *(const bf16x4*)&xl[base + lane * 4];
  bf16x4 o4 = *(const bf16x4*)&ob[base + lane * 4];
  float v[4];
  #pragma unroll
  for (int i = 0; i < 4; ++i) v[i] = (float)h4[i] + (float)l4[i] + (float)o4[i];
  float s = v[0] + v[1] + v[2] + v[3];
  #pragma unroll
  for (int off = 32; off > 0; off >>= 1) s += __shfl_down(s, off);
  float mu = __shfl(s, 0) * (1.f / 256.f);
  float var = 0.f;
  #pragma unroll
  for (int i = 0; i < 4; ++i) { float dd = v[i] - mu; var = fmaf(dd, dd, var); }
  #pragma unroll
  for (int off = 32; off > 0; off >>= 1) var += __shfl_down(var, off);
  float r = rsqrtf(__shfl(var, 0) * (1.f / 256.f) + LN_EPSF);
  float4 gv = *(const float4*)&g[lane * 4];
  float4 bv = *(const float4*)&bb[lane * 4];
  float gg[4] = {gv.x, gv.y, gv.z, gv.w};
  float bbv[4] = {bv.x, bv.y, bv.z, bv.w};
  bf16x4 hq, lq;
  #pragma unroll
  for (int i = 0; i < 4; ++i) {
    float o = (v[i] - mu) * r * gg[i] + bbv[i];
    __bf16 hh = (__bf16)o;
    hq[i] = hh;
    lq[i] = (__bf16)(o - (float)hh);
  }
  *(bf16x4*)&xh[base + lane * 4] = hq;
  *(bf16x4*)&xl[base + lane * 4] = lq;
}

// ---------------- fin[b][256] = reconstruct(x) at t=899
__global__ void extract_final(const __bf16* __restrict__ xh,
                              const __bf16* __restrict__ xl,
                              float* __restrict__ fin) {
  int b = blockIdx.x;
  int c = threadIdx.x;
  size_t o = ((size_t)b * SEQC + (SEQC - 1)) * D_MODELC + c;
  fin[(size_t)b * 256 + c] = (float)xh[o] + (float)xl[o];
}

// ---------------- final heads
__global__ __launch_bounds__(128) void heads_kernel(
    const float* __restrict__ fin,
    const float* __restrict__ cnt1_w, const float* __restrict__ cnt1_b,
    const float* __restrict__ cnt2_w, const float* __restrict__ cnt2_b,
    const float* __restrict__ col1_w, const float* __restrict__ col1_b,
    const float* __restrict__ col2_w, const float* __restrict__ col2_b,
    float* __restrict__ out) {
  int b = blockIdx.x;
  int tid = threadIdx.x;
  __shared__ float f[256];
  __shared__ float hc[128];
  __shared__ float hl[128];
  f[tid] = fin[b * 256 + tid];
  f[tid + 128] = fin[b * 256 + tid + 128];
  __syncthreads();
  float s1 = cnt1_b[tid], s2 = col1_b[tid];
  for (int c = 0; c < 256; ++c) {
    float v = f[c];
    s1 = fmaf(v, cnt1_w[c * 128 + tid], s1);
    s2 = fmaf(v, col1_w[c * 128 + tid], s2);
  }
  hc[tid] = fmaxf(s1, 0.f);
  hl[tid] = fmaxf(s2, 0.f);
  __syncthreads();
  if (tid == 0) {
    float t = cnt2_b[0];
    for (int j = 0; j < 128; ++j) t = fmaf(hc[j], cnt2_w[j], t);
    out[b] = fmaxf(t, 0.f);
  }
  if (tid < 10) {
    float t = col2_b[tid];
    for (int j = 0; j < 128; ++j) t = fmaf(hl[j], col2_w[j * 10 + tid], t);
    out[64 + b * 10 + tid] = fmaxf(t, 0.f);
  }
}

extern "C" void kernel_launch(void* const* d_in, const int* in_sizes, int n_in,
                              void* d_out, int out_size, void* d_ws, size_t ws_size,
                              hipStream_t stream) {
  const int*   grid   = (const int*)d_in[0];
  const float* cemb   = (const float*)d_in[1];
  const float* pemb   = (const float*)d_in[2];
  const float* in_w   = (const float*)d_in[3];
  const float* in_b   = (const float*)d_in[4];
  const float* conv_w = (const float*)d_in[5];
  const float* conv_b = (const float*)d_in[6];
  const float* xproj_w= (const float*)d_in[7];
  const float* xproj_b= (const float*)d_in[8];
  const float* A_log  = (const float*)d_in[9];
  const float* Dp     = (const float*)d_in[10];
  const float* out_w  = (const float*)d_in[11];
  const float* out_b  = (const float*)d_in[12];
  const float* ln_g   = (const float*)d_in[13];
  const float* ln_b   = (const float*)d_in[14];
  const float* cnt1_w = (const float*)d_in[15];
  const float* cnt1_b = (const float*)d_in[16];
  const float* cnt2_w = (const float*)d_in[17];
  const float* cnt2_b = (const float*)d_in[18];
  const float* col1_w = (const float*)d_in[19];
  const float* col1_b = (const float*)d_in[20];
  const float* col2_w = (const float*)d_in[21];
  const float* col2_b = (const float*)d_in[22];

  const int R = BATCHC * SEQC;  // 57600
  float* ws = (float*)d_ws;
  size_t off = 0;
  auto alloc = [&](size_t fl) { float* p = ws + off; off += (fl + 63) & ~(size_t)63; return p; };

  float*  fin   = alloc((size_t)BATCHC * 256);
  __bf16* wi    = (__bf16*)alloc((size_t)N_LAYERSC * 1024 * 256 / 2);
  __bf16* wx    = (__bf16*)alloc((size_t)N_LAYERSC * 32 * 512 / 2);
  __bf16* wo    = (__bf16*)alloc((size_t)N_LAYERSC * 256 * 512 / 2);
  __bf16* xh    = (__bf16*)alloc((size_t)R * 256 / 2);
  __bf16* xl    = (__bf16*)alloc((size_t)R * 256 / 2);
  __bf16* xsyc  = (__bf16*)alloc((size_t)R * 512 / 2);   // xs then yc
  float*  gateob= alloc((size_t)R * 512 / 2);            // gate bf16, then ob bf16
  __bf16* xc    = (__bf16*)alloc((size_t)R * 512 / 2);
  __bf16* ssm   = (__bf16*)alloc((size_t)R * 32 / 2);
  __bf16* hend  = (__bf16*)alloc((size_t)BATCHC * NCH * 512 * 16 / 2);
  __bf16* Pp    = (__bf16*)alloc((size_t)BATCHC * NCH * 512 * 16 / 2);
  __bf16* gate  = (__bf16*)gateob;
  __bf16* obb   = (__bf16*)gateob;   // out-proj result (gate dead after phase3)

  // weight prep (once per call)
  wprep<<<dim3(1024, N_LAYERSC), 256, 0, stream>>>(in_w, wi, 256, 1024, 8);
  wprep<<<dim3(64, N_LAYERSC), 256, 0, stream>>>(xproj_w, wx, 512, 32, 9);
  wprep<<<dim3(512, N_LAYERSC), 256, 0, stream>>>(out_w, wo, 512, 256, 9);

  embed_kernel<<<R, 256, 0, stream>>>(grid, cemb, pemb, xh, xl);

  for (int l = 0; l < N_LAYERSC; ++l) {
    // in-proj: xs (bf16) + gate = silu(res) (bf16)
    gemm_bf16<<<dim3(8, R / 128), 256, 0, stream>>>(
        xh, wi + (size_t)l * 1024 * 256, in_b + l * 1024,
        xsyc, gate, R, 1024, 256, 2);
    conv_silu<<<(R * 64 + 255) / 256, 256, 0, stream>>>(
        xsyc, conv_w + (size_t)l * 512 * 4, conv_b + l * 512, xc, R * 64);
    // x-proj: ssm bf16, softplus fused on delta cols
    gemm_bf16<<<dim3(1, R / 128), 256, 0, stream>>>(
        xc, wx + (size_t)l * 32 * 512, xproj_b + l * 32,
        ssm, nullptr, R, 32, 512, 1);
    scan_phase1<<<dim3(BATCHC, 2, NCH), 256, 0, stream>>>(
        ssm, A_log + (size_t)l * 512 * 16, xc, hend, Pp);
    scan_combine<<<dim3(BATCHC, 8), 64, 0, stream>>>(hend, Pp);
    scan_phase3<<<dim3(BATCHC, 2, NCH), 256, 0, stream>>>(
        ssm, A_log + (size_t)l * 512 * 16, Dp + l * 512, xc, gate, hend, xsyc);
    // out-proj: ob bf16 (overwrites gate region — gate dead after phase3)
    gemm_bf16<<<dim3(2, R / 128), 256, 0, stream>>>(
        xsyc, wo + (size_t)l * 256 * 512, out_b + l * 256,
        obb, nullptr, R, 256, 512, 3);
    add_ln<<<R / 4, 256, 0, stream>>>(xh, xl, obb, ln_g, ln_b);
  }

  extract_final<<<BATCHC, 256, 0, stream>>>(xh, xl, fin);
  heads_kernel<<<BATCHC, 128, 0, stream>>>(
      fin, cnt1_w, cnt1_b, cnt2_w, cnt2_b, col1_w, col1_b, col2_w, col2_b,
      (float*)d_out);
}

// Round 13
// 1996.843 us; speedup vs baseline: 1.3846x; 1.1639x over previous
//
#include <hip/hip_runtime.h>
#include <cstdint>

#define D_MODELC 256
#define N_LAYERSC 4
#define BATCHC 64
#define SEQC 900
#define NCH 10
#define CT 90
#define SUB 45
#define LN_EPSF 1e-5f
#define LOG2E 1.44269504088896f

typedef __bf16 bf16x8 __attribute__((ext_vector_type(8)));
typedef __bf16 bf16x4 __attribute__((ext_vector_type(4)));
typedef float floatx4 __attribute__((ext_vector_type(4)));

#if defined(__has_builtin)
#if __has_builtin(__builtin_amdgcn_exp2f)
#define EXP2F __builtin_amdgcn_exp2f
#endif
#endif
#ifndef EXP2F
#define EXP2F exp2f
#endif

__device__ inline float sp(float v) { return (v > 20.f) ? v : log1pf(__expf(v)); }
__device__ inline float silu(float v) { return v / (1.f + __expf(-v)); }

// ---------------- weight transpose + cvt: W (L,K,N) -> Wb (L,N,K) bf16
__global__ void wprep(const float* __restrict__ W, __bf16* __restrict__ Wb,
                      int K, int N, int kshift) {
  int l = blockIdx.y;
  int idx = blockIdx.x * 256 + threadIdx.x;
  if (idx >= N * K) return;
  int n = idx >> kshift, k = idx & (K - 1);
  Wb[(size_t)l * N * K + idx] = (__bf16)W[(size_t)l * K * N + (size_t)k * N + n];
}

// ---------------- embed -> split bf16 x
__global__ void embed_kernel(const int* __restrict__ grid,
                             const float* __restrict__ cemb,
                             const float* __restrict__ pemb,
                             __bf16* __restrict__ xh, __bf16* __restrict__ xl) {
  int row = blockIdx.x;
  int c = threadIdx.x;
  int s = row % SEQC;
  int g = grid[row];
  float v = cemb[g * D_MODELC + c] + pemb[s * D_MODELC + c];
  size_t o = (size_t)row * D_MODELC + c;
  __bf16 hh = (__bf16)v;
  xh[o] = hh;
  xl[o] = (__bf16)(v - (float)hh);
}

// ---------------- bf16 MFMA GEMM: C = A(MxK) * W^T(NxK) + bias
// 128x128 tile, 4 waves (2x2), BK=32, single-buffer (r7 form — fastest).
// 1D grid with XCD supertile swizzle: within a supertile of 8 row-tiles,
// linear = col*8 + row_within  ->  (if dispatch is ID%8 round-robin) the 8
// col-tiles of one row-tile share an XCD -> A-tile fetched once per XCD.
// MODE 1: bf16 Cb, softplus cols<16 (x-proj).  MODE 2: in-proj split+silu.
// MODE 3: bf16 Cb plain.  GUARD: compile-time col guards (x-proj only).
#define GLDA 44
template<int MODE, bool GUARD>
__global__ __launch_bounds__(256) void gemm_bf16(
    const __bf16* __restrict__ A, const __bf16* __restrict__ W,
    const float* __restrict__ bias,
    __bf16* __restrict__ Cb, __bf16* __restrict__ Cg,
    int M, int N, int K, int nrow, int ncol) {
  __shared__ __attribute__((aligned(16))) __bf16 As[128 * GLDA];
  __shared__ __attribute__((aligned(16))) __bf16 Bs[128 * GLDA];
  int id = blockIdx.x;
  int row, col;
  {
    int fullsup = (nrow >> 3) * 8 * ncol;
    if (id < fullsup) {
      int per = ncol * 8;
      int s = id / per, r = id % per;
      col = r >> 3;
      row = (s << 3) + (r & 7);
    } else {
      int r = id - fullsup;
      int tr = nrow & 7;
      col = r / tr;
      row = (nrow & ~7) + r % tr;
    }
  }
  int tid = threadIdx.x, lane = tid & 63, w = tid >> 6;
  int bm = row * 128, bn = col * 128;
  int wm = (w >> 1) * 64, wn = (w & 1) * 64;
  int lm = lane & 15, kq = lane >> 4;
  bool wactive = !GUARD || (bn + wn < N);

  floatx4 acc[4][4];
  floatx4 zero = {0.f, 0.f, 0.f, 0.f};
  #pragma unroll
  for (int i = 0; i < 4; ++i)
    #pragma unroll
    for (int j = 0; j < 4; ++j) acc[i][j] = zero;

  int r0 = tid >> 1;          // 0..127
  int kb = (tid & 1) * 16;    // 0 / 16

  for (int k0 = 0; k0 < K; k0 += 32) {
    __syncthreads();
    {
      size_t aoff = (size_t)(bm + r0) * K + k0 + kb;
      *(bf16x8*)&As[r0 * GLDA + kb]     = *(const bf16x8*)&A[aoff];
      *(bf16x8*)&As[r0 * GLDA + kb + 8] = *(const bf16x8*)&A[aoff + 8];
      int nr = bn + r0;
      if (!GUARD || nr < N) {
        size_t boff = (size_t)nr * K + k0 + kb;
        *(bf16x8*)&Bs[r0 * GLDA + kb]     = *(const bf16x8*)&W[boff];
        *(bf16x8*)&Bs[r0 * GLDA + kb + 8] = *(const bf16x8*)&W[boff + 8];
      } else {
        uint4 zu = make_uint4(0, 0, 0, 0);
        *(uint4*)&Bs[r0 * GLDA + kb] = zu;
        *(uint4*)&Bs[r0 * GLDA + kb + 8] = zu;
      }
    }
    __syncthreads();
    if (wactive) {
      bf16x8 fa[4], fb[4];
      #pragma unroll
      for (int mt = 0; mt < 4; ++mt)
        fa[mt] = *(const bf16x8*)&As[(wm + mt * 16 + lm) * GLDA + kq * 8];
      #pragma unroll
      for (int nt = 0; nt < 4; ++nt)
        fb[nt] = *(const bf16x8*)&Bs[(wn + nt * 16 + lm) * GLDA + kq * 8];
      #pragma unroll
      for (int mt = 0; mt < 4; ++mt)
        #pragma unroll
        for (int nt = 0; nt < 4; ++nt)
          acc[mt][nt] = __builtin_amdgcn_mfma_f32_16x16x32_bf16(fa[mt], fb[nt], acc[mt][nt], 0, 0, 0);
    }
  }

  if (!wactive) return;
  #pragma unroll
  for (int mt = 0; mt < 4; ++mt)
    #pragma unroll
    for (int nt = 0; nt < 4; ++nt) {
      int col2 = bn + wn + nt * 16 + lm;
      if (GUARD && col2 >= N) continue;
      float bz = bias[col2];
      #pragma unroll
      for (int i = 0; i < 4; ++i) {
        int rr = bm + wm + mt * 16 + kq * 4 + i;
        float v = acc[mt][nt][i] + bz;
        if (MODE == 1) {
          if (col2 < 16) v = sp(v);          // softplus(delta) once here
          Cb[(size_t)rr * N + col2] = (__bf16)v;
        } else if (MODE == 2) {
          if (col2 < 512) Cb[(size_t)rr * 512 + col2] = (__bf16)v;
          else            Cg[(size_t)rr * 512 + col2 - 512] = (__bf16)silu(v);
        } else {
          Cb[(size_t)rr * N + col2] = (__bf16)v;
        }
      }
    }
}

// ---------------- depthwise causal conv (k=4) + SiLU, bf16 in/out, 8 ch/thread
__global__ void conv_silu(const __bf16* __restrict__ xs,
                          const float* __restrict__ cw,
                          const float* __restrict__ cb,
                          __bf16* __restrict__ xc, int total) {
  int idx = blockIdx.x * 256 + threadIdx.x;   // < R*64
  if (idx >= total) return;
  int d8 = (idx & 63) * 8;
  int bt = idx >> 6;
  int t = bt % SEQC;
  const __bf16* base = xs + (size_t)(bt - t) * 512 + d8;
  float wv[8][4];
  #pragma unroll
  for (int e = 0; e < 8; ++e) {
    float4 wq = *(const float4*)&cw[(d8 + e) * 4];
    wv[e][0] = wq.x; wv[e][1] = wq.y; wv[e][2] = wq.z; wv[e][3] = wq.w;
  }
  float4 b0 = *(const float4*)&cb[d8];
  float4 b1 = *(const float4*)&cb[d8 + 4];
  float acc[8] = {b0.x, b0.y, b0.z, b0.w, b1.x, b1.y, b1.z, b1.w};
  #pragma unroll
  for (int j = 0; j < 4; ++j) {
    int ts = t - 3 + j;
    if (ts >= 0) {
      bf16x8 v = *(const bf16x8*)&base[(size_t)ts * 512];
      #pragma unroll
      for (int e = 0; e < 8; ++e) acc[e] = fmaf(wv[e][j], (float)v[e], acc[e]);
    }
  }
  bf16x8 o;
  #pragma unroll
  for (int e = 0; e < 8; ++e) o[e] = (__bf16)silu(acc[e]);
  *(bf16x8*)&xc[(size_t)bt * 512 + d8] = o;
}

// ---------------- scan phase 1: per-chunk local scan (h=0) -> hend, P (bf16)
__global__ __launch_bounds__(256, 4) void scan_phase1(
    const __bf16* __restrict__ ssm, const float* __restrict__ A_log,
    const __bf16* __restrict__ xc,
    __bf16* __restrict__ hend, __bf16* __restrict__ Pp) {
  __shared__ float sb[SUB * 32];
  __shared__ __bf16 xsb[SUB * 256];
  int b = blockIdx.x, half = blockIdx.y, c = blockIdx.z;
  int tid = threadIdx.x;
  int dg0 = half * 256;
  int d = dg0 + tid;
  float a2[16];
  #pragma unroll
  for (int n = 0; n < 16; ++n) a2[n] = -__expf(A_log[d * 16 + n]) * LOG2E;
  float h[16] = {}, S[16] = {};
  size_t rowbase = (size_t)b * SEQC + c * CT;

  for (int sub = 0; sub < 2; ++sub) {
    int ts0 = sub * SUB;
    __syncthreads();
    for (int i = tid; i < SUB * 8; i += 256) {
      int tt = i >> 3, n4 = (i & 7) * 4;
      bf16x4 v = *(const bf16x4*)&ssm[(rowbase + ts0 + tt) * 32 + n4];
      float4 f = {(float)v[0], (float)v[1], (float)v[2], (float)v[3]};
      *(float4*)&sb[tt * 32 + n4] = f;
    }
    for (int i = tid; i < SUB * 64; i += 256) {
      int tt = i >> 6, j4 = (i & 63) * 4;
      *(bf16x4*)&xsb[tt * 256 + j4] =
          *(const bf16x4*)&xc[(rowbase + ts0 + tt) * 512 + dg0 + j4];
    }
    __syncthreads();
    for (int tt = 0; tt < SUB; ++tt) {
      const float4* dv = (const float4*)&sb[tt * 32];
      float4 d0 = dv[0], d1 = dv[1], d2 = dv[2], d3 = dv[3];
      float4 e0 = dv[4], e1 = dv[5], e2 = dv[6], e3 = dv[7];
      float del[16] = {d0.x, d0.y, d0.z, d0.w, d1.x, d1.y, d1.z, d1.w,
                       d2.x, d2.y, d2.z, d2.w, d3.x, d3.y, d3.z, d3.w};
      float Bv[16]  = {e0.x, e0.y, e0.z, e0.w, e1.x, e1.y, e1.z, e1.w,
                       e2.x, e2.y, e2.z, e2.w, e3.x, e3.y, e3.z, e3.w};
      float xv = (float)xsb[tt * 256 + tid];
      #pragma unroll
      for (int n = 0; n < 16; ++n) {
        S[n] += del[n];
        float e = EXP2F(a2[n] * del[n]);
        h[n] = fmaf(h[n], e, xv * Bv[n]);
      }
    }
  }
  size_t base = ((size_t)(b * NCH + c) * 512 + d) * 16;
  bf16x8 h0, h1, p0, p1;
  #pragma unroll
  for (int n = 0; n < 8; ++n) {
    h0[n] = (__bf16)h[n]; h1[n] = (__bf16)h[n + 8];
    p0[n] = (__bf16)EXP2F(a2[n] * S[n]);
    p1[n] = (__bf16)EXP2F(a2[n + 8] * S[n + 8]);
  }
  *(bf16x8*)&hend[base] = h0; *(bf16x8*)&hend[base + 8] = h1;
  *(bf16x8*)&Pp[base] = p0;   *(bf16x8*)&Pp[base + 8] = p1;
}

// ---------------- scan phase 2: sequential carry composition (hend -> hin in place)
__global__ __launch_bounds__(64) void scan_combine(
    __bf16* __restrict__ hend, const __bf16* __restrict__ Pp) {
  int b = blockIdx.x;
  int d = blockIdx.y * 64 + threadIdx.x;
  float hp[16] = {};
  for (int c = 0; c < NCH; ++c) {
    size_t base = ((size_t)(b * NCH + c) * 512 + d) * 16;
    bf16x8 he0 = *(const bf16x8*)&hend[base];
    bf16x8 he1 = *(const bf16x8*)&hend[base + 8];
    bf16x8 pp0 = *(const bf16x8*)&Pp[base];
    bf16x8 pp1 = *(const bf16x8*)&Pp[base + 8];
    bf16x8 o0, o1;
    #pragma unroll
    for (int n = 0; n < 8; ++n) {
      o0[n] = (__bf16)hp[n]; o1[n] = (__bf16)hp[n + 8];
      hp[n]     = fmaf((float)pp0[n], hp[n],     (float)he0[n]);
      hp[n + 8] = fmaf((float)pp1[n], hp[n + 8], (float)he1[n]);
    }
    *(bf16x8*)&hend[base] = o0; *(bf16x8*)&hend[base + 8] = o1;
  }
}

// ---------------- scan phase 3: local scan with carry, y, gate -> yc bf16
__global__ __launch_bounds__(256, 4) void scan_phase3(
    const __bf16* __restrict__ ssm, const float* __restrict__ A_log,
    const float* __restrict__ Dp, const __bf16* __restrict__ xc,
    const __bf16* __restrict__ gate, const __bf16* __restrict__ hin,
    __bf16* __restrict__ yc) {
  __shared__ float sb[SUB * 32];
  __shared__ __bf16 xsb[SUB * 256];
  int b = blockIdx.x, half = blockIdx.y, c = blockIdx.z;
  int tid = threadIdx.x;
  int dg0 = half * 256;
  int d = dg0 + tid;
  float a2[16];
  #pragma unroll
  for (int n = 0; n < 16; ++n) a2[n] = -__expf(A_log[d * 16 + n]) * LOG2E;
  float Dv = Dp[d];
  float h[16];
  {
    size_t base = ((size_t)(b * NCH + c) * 512 + d) * 16;
    bf16x8 h0 = *(const bf16x8*)&hin[base];
    bf16x8 h1 = *(const bf16x8*)&hin[base + 8];
    #pragma unroll
    for (int n = 0; n < 8; ++n) { h[n] = (float)h0[n]; h[n + 8] = (float)h1[n]; }
  }
  size_t rowbase = (size_t)b * SEQC + c * CT;

  for (int sub = 0; sub < 2; ++sub) {
    int ts0 = sub * SUB;
    __syncthreads();
    for (int i = tid; i < SUB * 8; i += 256) {
      int tt = i >> 3, n4 = (i & 7) * 4;
      bf16x4 v = *(const bf16x4*)&ssm[(rowbase + ts0 + tt) * 32 + n4];
      float4 f = {(float)v[0], (float)v[1], (float)v[2], (float)v[3]};
      *(float4*)&sb[tt * 32 + n4] = f;
    }
    for (int i = tid; i < SUB * 64; i += 256) {
      int tt = i >> 6, j4 = (i & 63) * 4;
      *(bf16x4*)&xsb[tt * 256 + j4] =
          *(const bf16x4*)&xc[(rowbase + ts0 + tt) * 512 + dg0 + j4];
    }
    __syncthreads();
    for (int tt = 0; tt < SUB; ++tt) {
      const float4* dv = (const float4*)&sb[tt * 32];
      float4 d0 = dv[0], d1 = dv[1], d2 = dv[2], d3 = dv[3];
      float4 e0 = dv[4], e1 = dv[5], e2 = dv[6], e3 = dv[7];
      float del[16] = {d0.x, d0.y, d0.z, d0.w, d1.x, d1.y, d1.z, d1.w,
                       d2.x, d2.y, d2.z, d2.w, d3.x, d3.y, d3.z, d3.w};
      float Bv[16]  = {e0.x, e0.y, e0.z, e0.w, e1.x, e1.y, e1.z, e1.w,
                       e2.x, e2.y, e2.z, e2.w, e3.x, e3.y, e3.z, e3.w};
      float xv = (float)xsb[tt * 256 + tid];
      float y0 = 0.f, y1 = 0.f, y2 = 0.f, y3 = 0.f;
      #pragma unroll
      for (int n = 0; n < 4; ++n) {
        float e = EXP2F(a2[n] * del[n]);
        h[n] = fmaf(h[n], e, xv * Bv[n]);
        y0 = fmaf(h[n], Bv[n], y0);
      }
      #pragma unroll
      for (int n = 4; n < 8; ++n) {
        float e = EXP2F(a2[n] * del[n]);
        h[n] = fmaf(h[n], e, xv * Bv[n]);
        y1 = fmaf(h[n], Bv[n], y1);
      }
      #pragma unroll
      for (int n = 8; n < 12; ++n) {
        float e = EXP2F(a2[n] * del[n]);
        h[n] = fmaf(h[n], e, xv * Bv[n]);
        y2 = fmaf(h[n], Bv[n], y2);
      }
      #pragma unroll
      for (int n = 12; n < 16; ++n) {
        float e = EXP2F(a2[n] * del[n]);
        h[n] = fmaf(h[n], e, xv * Bv[n]);
        y3 = fmaf(h[n], Bv[n], y3);
      }
      xsb[tt * 256 + tid] = (__bf16)fmaf(Dv, xv, (y0 + y1) + (y2 + y3));
    }
    __syncthreads();
    for (int i = tid; i < SUB * 64; i += 256) {
      int tt = i >> 6, j4 = (i & 63) * 4;
      size_t o = (rowbase + ts0 + tt) * 512 + dg0 + j4;
      bf16x4 y4 = *(const bf16x4*)&xsb[tt * 256 + j4];
      bf16x4 g4 = *(const bf16x4*)&gate[o];
      bf16x4 r;
      #pragma unroll
      for (int e = 0; e < 4; ++e) r[e] = (__bf16)((float)y4[e] * (float)g4[e]);
      *(bf16x4*)&yc[o] = r;
    }
  }
}

// ---------------- x = LayerNorm(reconstruct(xh,xl) + ob_bf16), re-split; 4 rows/block
__global__ __launch_bounds__(256) void add_ln(
    __bf16* __restrict__ xh, __bf16* __restrict__ xl,
    const __bf16* __restrict__ ob,
    const float* __restrict__ g, const float* __restrict__ bb) {
  int lane = threadIdx.x & 63;
  size_t base = ((size_t)blockIdx.x * 4 + (threadIdx.x >> 6)) * 256;
  bf16x4 h4 = *(const bf16x4*)&xh[base + lane * 4];
  bf16x4 l4 = *(const bf16x4*)&xl[base + lane * 4];
  bf16x4 o4 = *(const bf16x4*)&ob[base + lane * 4];
  float v[4];
  #pragma unroll
  for (int i = 0; i < 4; ++i) v[i] = (float)h4[i] + (float)l4[i] + (float)o4[i];
  float s = v[0] + v[1] + v[2] + v[3];
  #pragma unroll
  for (int off = 32; off > 0; off >>= 1) s += __shfl_down(s, off);
  float mu = __shfl(s, 0) * (1.f / 256.f);
  float var = 0.f;
  #pragma unroll
  for (int i = 0; i < 4; ++i) { float dd = v[i] - mu; var = fmaf(dd, dd, var); }
  #pragma unroll
  for (int off = 32; off > 0; off >>= 1) var += __shfl_down(var, off);
  float r = rsqrtf(__shfl(var, 0) * (1.f / 256.f) + LN_EPSF);
  float4 gv = *(const float4*)&g[lane * 4];
  float4 bv = *(const float4*)&bb[lane * 4];
  float gg[4] = {gv.x, gv.y, gv.z, gv.w};
  float bbv[4] = {bv.x, bv.y, bv.z, bv.w};
  bf16x4 hq, lq;
  #pragma unroll
  for (int i = 0; i < 4; ++i) {
    float o = (v[i] - mu) * r * gg[i] + bbv[i];
    __bf16 hh = (__bf16)o;
    hq[i] = hh;
    lq[i] = (__bf16)(o - (float)hh);
  }
  *(bf16x4*)&xh[base + lane * 4] = hq;
  *(bf16x4*)&xl[base + lane * 4] = lq;
}

// ---------------- fin[b][256] = reconstruct(x) at t=899
__global__ void extract_final(const __bf16* __restrict__ xh,
                              const __bf16* __restrict__ xl,
                              float* __restrict__ fin) {
  int b = blockIdx.x;
  int c = threadIdx.x;
  size_t o = ((size_t)b * SEQC + (SEQC - 1)) * D_MODELC + c;
  fin[(size_t)b * 256 + c] = (float)xh[o] + (float)xl[o];
}

// ---------------- final heads
__global__ __launch_bounds__(128) void heads_kernel(
    const float* __restrict__ fin,
    const float* __restrict__ cnt1_w, const float* __restrict__ cnt1_b,
    const float* __restrict__ cnt2_w, const float* __restrict__ cnt2_b,
    const float* __restrict__ col1_w, const float* __restrict__ col1_b,
    const float* __restrict__ col2_w, const float* __restrict__ col2_b,
    float* __restrict__ out) {
  int b = blockIdx.x;
  int tid = threadIdx.x;
  __shared__ float f[256];
  __shared__ float hc[128];
  __shared__ float hl[128];
  f[tid] = fin[b * 256 + tid];
  f[tid + 128] = fin[b * 256 + tid + 128];
  __syncthreads();
  float s1 = cnt1_b[tid], s2 = col1_b[tid];
  for (int c = 0; c < 256; ++c) {
    float v = f[c];
    s1 = fmaf(v, cnt1_w[c * 128 + tid], s1);
    s2 = fmaf(v, col1_w[c * 128 + tid], s2);
  }
  hc[tid] = fmaxf(s1, 0.f);
  hl[tid] = fmaxf(s2, 0.f);
  __syncthreads();
  if (tid == 0) {
    float t = cnt2_b[0];
    for (int j = 0; j < 128; ++j) t = fmaf(hc[j], cnt2_w[j], t);
    out[b] = fmaxf(t, 0.f);
  }
  if (tid < 10) {
    float t = col2_b[tid];
    for (int j = 0; j < 128; ++j) t = fmaf(hl[j], col2_w[j * 10 + tid], t);
    out[64 + b * 10 + tid] = fmaxf(t, 0.f);
  }
}

extern "C" void kernel_launch(void* const* d_in, const int* in_sizes, int n_in,
                              void* d_out, int out_size, void* d_ws, size_t ws_size,
                              hipStream_t stream) {
  const int*   grid   = (const int*)d_in[0];
  const float* cemb   = (const float*)d_in[1];
  const float* pemb   = (const float*)d_in[2];
  const float* in_w   = (const float*)d_in[3];
  const float* in_b   = (const float*)d_in[4];
  const float* conv_w = (const float*)d_in[5];
  const float* conv_b = (const float*)d_in[6];
  const float* xproj_w= (const float*)d_in[7];
  const float* xproj_b= (const float*)d_in[8];
  const float* A_log  = (const float*)d_in[9];
  const float* Dp     = (const float*)d_in[10];
  const float* out_w  = (const float*)d_in[11];
  const float* out_b  = (const float*)d_in[12];
  const float* ln_g   = (const float*)d_in[13];
  const float* ln_b   = (const float*)d_in[14];
  const float* cnt1_w = (const float*)d_in[15];
  const float* cnt1_b = (const float*)d_in[16];
  const float* cnt2_w = (const float*)d_in[17];
  const float* cnt2_b = (const float*)d_in[18];
  const float* col1_w = (const float*)d_in[19];
  const float* col1_b = (const float*)d_in[20];
  const float* col2_w = (const float*)d_in[21];
  const float* col2_b = (const float*)d_in[22];

  const int R = BATCHC * SEQC;  // 57600
  float* ws = (float*)d_ws;
  size_t off = 0;
  auto alloc = [&](size_t fl) { float* p = ws + off; off += (fl + 63) & ~(size_t)63; return p; };

  float*  fin   = alloc((size_t)BATCHC * 256);
  __bf16* wi    = (__bf16*)alloc((size_t)N_LAYERSC * 1024 * 256 / 2);
  __bf16* wx    = (__bf16*)alloc((size_t)N_LAYERSC * 32 * 512 / 2);
  __bf16* wo    = (__bf16*)alloc((size_t)N_LAYERSC * 256 * 512 / 2);
  __bf16* xh    = (__bf16*)alloc((size_t)R * 256 / 2);
  __bf16* xl    = (__bf16*)alloc((size_t)R * 256 / 2);
  __bf16* xsyc  = (__bf16*)alloc((size_t)R * 512 / 2);   // xs then yc
  float*  gateob= alloc((size_t)R * 512 / 2);            // gate bf16, then ob bf16
  __bf16* xc    = (__bf16*)alloc((size_t)R * 512 / 2);
  __bf16* ssm   = (__bf16*)alloc((size_t)R * 32 / 2);
  __bf16* hend  = (__bf16*)alloc((size_t)BATCHC * NCH * 512 * 16 / 2);
  __bf16* Pp    = (__bf16*)alloc((size_t)BATCHC * NCH * 512 * 16 / 2);
  __bf16* gate  = (__bf16*)gateob;
  __bf16* obb   = (__bf16*)gateob;   // out-proj result (gate dead after phase3)

  // weight prep (once per call)
  wprep<<<dim3(1024, N_LAYERSC), 256, 0, stream>>>(in_w, wi, 256, 1024, 8);
  wprep<<<dim3(64, N_LAYERSC), 256, 0, stream>>>(xproj_w, wx, 512, 32, 9);
  wprep<<<dim3(512, N_LAYERSC), 256, 0, stream>>>(out_w, wo, 512, 256, 9);

  embed_kernel<<<R, 256, 0, stream>>>(grid, cemb, pemb, xh, xl);

  const int NROW = R / 128;   // 450
  for (int l = 0; l < N_LAYERSC; ++l) {
    // in-proj: xs (bf16) + gate = silu(res) (bf16); 1D swizzled grid
    gemm_bf16<2, false><<<NROW * 8, 256, 0, stream>>>(
        xh, wi + (size_t)l * 1024 * 256, in_b + l * 1024,
        xsyc, gate, R, 1024, 256, NROW, 8);
    conv_silu<<<(R * 64 + 255) / 256, 256, 0, stream>>>(
        xsyc, conv_w + (size_t)l * 512 * 4, conv_b + l * 512, xc, R * 64);
    // x-proj: ssm bf16, softplus fused on delta cols (guarded, 1 col tile)
    gemm_bf16<1, true><<<NROW, 256, 0, stream>>>(
        xc, wx + (size_t)l * 32 * 512, xproj_b + l * 32,
        ssm, nullptr, R, 32, 512, NROW, 1);
    scan_phase1<<<dim3(BATCHC, 2, NCH), 256, 0, stream>>>(
        ssm, A_log + (size_t)l * 512 * 16, xc, hend, Pp);
    scan_combine<<<dim3(BATCHC, 8), 64, 0, stream>>>(hend, Pp);
    scan_phase3<<<dim3(BATCHC, 2, NCH), 256, 0, stream>>>(
        ssm, A_log + (size_t)l * 512 * 16, Dp + l * 512, xc, gate, hend, xsyc);
    // out-proj: ob bf16 (overwrites gate region — gate dead after phase3)
    gemm_bf16<3, false><<<NROW * 2, 256, 0, stream>>>(
        xsyc, wo + (size_t)l * 256 * 512, out_b + l * 256,
        obb, nullptr, R, 256, 512, NROW, 2);
    add_ln<<<R / 4, 256, 0, stream>>>(xh, xl, obb, ln_g, ln_b);
  }

  extract_final<<<BATCHC, 256, 0, stream>>>(xh, xl, fin);
  heads_kernel<<<BATCHC, 128, 0, stream>>>(
      fin, cnt1_w, cnt1_b, cnt2_w, cnt2_b, col1_w, col1_b, col2_w, col2_b,
      (float*)d_out);
}

// Round 14
// 1918.938 us; speedup vs baseline: 1.4408x; 1.0406x over previous
//
#include <hip/hip_runtime.h>
#include <cstdint>

#define D_MODELC 256
#define N_LAYERSC 4
#define BATCHC 64
#define SEQC 900
#define NCH 10
#define CT 90
#define SUB 45
#define LN_EPSF 1e-5f
#define LOG2E 1.44269504088896f

typedef __bf16 bf16x8 __attribute__((ext_vector_type(8)));
typedef __bf16 bf16x4 __attribute__((ext_vector_type(4)));
typedef float floatx4 __attribute__((ext_vector_type(4)));
typedef float floatx2 __attribute__((ext_vector_type(2)));

#if defined(__has_builtin)
#if __has_builtin(__builtin_amdgcn_exp2f)
#define EXP2F __builtin_amdgcn_exp2f
#endif
#endif
#ifndef EXP2F
#define EXP2F exp2f
#endif

__device__ inline float sp(float v) { return (v > 20.f) ? v : log1pf(__expf(v)); }
__device__ inline float silu(float v) { return v / (1.f + __expf(-v)); }

// ---------------- weight transpose + cvt: W (L,K,N) -> Wb (L,N,K) bf16
__global__ void wprep(const float* __restrict__ W, __bf16* __restrict__ Wb,
                      int K, int N, int kshift) {
  int l = blockIdx.y;
  int idx = blockIdx.x * 256 + threadIdx.x;
  if (idx >= N * K) return;
  int n = idx >> kshift, k = idx & (K - 1);
  Wb[(size_t)l * N * K + idx] = (__bf16)W[(size_t)l * K * N + (size_t)k * N + n];
}

// ---------------- embed -> split bf16 x
__global__ void embed_kernel(const int* __restrict__ grid,
                             const float* __restrict__ cemb,
                             const float* __restrict__ pemb,
                             __bf16* __restrict__ xh, __bf16* __restrict__ xl) {
  int row = blockIdx.x;
  int c = threadIdx.x;
  int s = row % SEQC;
  int g = grid[row];
  float v = cemb[g * D_MODELC + c] + pemb[s * D_MODELC + c];
  size_t o = (size_t)row * D_MODELC + c;
  __bf16 hh = (__bf16)v;
  xh[o] = hh;
  xl[o] = (__bf16)(v - (float)hh);
}

// ---------------- bf16 MFMA GEMM: C = A(MxK) * W^T(NxK) + bias
// 128x128 tile, 4 waves (2x2), BK=32, single-buffer. XCD supertile swizzle.
// MODE 1: bf16 Cb, softplus cols<16 (x-proj).  MODE 2: in-proj split+silu.
// MODE 3: bf16 Cb plain.  GUARD: compile-time col guards (x-proj only).
#define GLDA 44
template<int MODE, bool GUARD>
__global__ __launch_bounds__(256) void gemm_bf16(
    const __bf16* __restrict__ A, const __bf16* __restrict__ W,
    const float* __restrict__ bias,
    __bf16* __restrict__ Cb, __bf16* __restrict__ Cg,
    int M, int N, int K, int nrow, int ncol) {
  __shared__ __attribute__((aligned(16))) __bf16 As[128 * GLDA];
  __shared__ __attribute__((aligned(16))) __bf16 Bs[128 * GLDA];
  int id = blockIdx.x;
  int row, col;
  {
    int fullsup = (nrow >> 3) * 8 * ncol;
    if (id < fullsup) {
      int per = ncol * 8;
      int s = id / per, r = id % per;
      col = r >> 3;
      row = (s << 3) + (r & 7);
    } else {
      int r = id - fullsup;
      int tr = nrow & 7;
      col = r / tr;
      row = (nrow & ~7) + r % tr;
    }
  }
  int tid = threadIdx.x, lane = tid & 63, w = tid >> 6;
  int bm = row * 128, bn = col * 128;
  int wm = (w >> 1) * 64, wn = (w & 1) * 64;
  int lm = lane & 15, kq = lane >> 4;
  bool wactive = !GUARD || (bn + wn < N);

  floatx4 acc[4][4];
  floatx4 zero = {0.f, 0.f, 0.f, 0.f};
  #pragma unroll
  for (int i = 0; i < 4; ++i)
    #pragma unroll
    for (int j = 0; j < 4; ++j) acc[i][j] = zero;

  int r0 = tid >> 1;          // 0..127
  int kb = (tid & 1) * 16;    // 0 / 16

  for (int k0 = 0; k0 < K; k0 += 32) {
    __syncthreads();
    {
      size_t aoff = (size_t)(bm + r0) * K + k0 + kb;
      *(bf16x8*)&As[r0 * GLDA + kb]     = *(const bf16x8*)&A[aoff];
      *(bf16x8*)&As[r0 * GLDA + kb + 8] = *(const bf16x8*)&A[aoff + 8];
      int nr = bn + r0;
      if (!GUARD || nr < N) {
        size_t boff = (size_t)nr * K + k0 + kb;
        *(bf16x8*)&Bs[r0 * GLDA + kb]     = *(const bf16x8*)&W[boff];
        *(bf16x8*)&Bs[r0 * GLDA + kb + 8] = *(const bf16x8*)&W[boff + 8];
      } else {
        uint4 zu = make_uint4(0, 0, 0, 0);
        *(uint4*)&Bs[r0 * GLDA + kb] = zu;
        *(uint4*)&Bs[r0 * GLDA + kb + 8] = zu;
      }
    }
    __syncthreads();
    if (wactive) {
      bf16x8 fa[4], fb[4];
      #pragma unroll
      for (int mt = 0; mt < 4; ++mt)
        fa[mt] = *(const bf16x8*)&As[(wm + mt * 16 + lm) * GLDA + kq * 8];
      #pragma unroll
      for (int nt = 0; nt < 4; ++nt)
        fb[nt] = *(const bf16x8*)&Bs[(wn + nt * 16 + lm) * GLDA + kq * 8];
      #pragma unroll
      for (int mt = 0; mt < 4; ++mt)
        #pragma unroll
        for (int nt = 0; nt < 4; ++nt)
          acc[mt][nt] = __builtin_amdgcn_mfma_f32_16x16x32_bf16(fa[mt], fb[nt], acc[mt][nt], 0, 0, 0);
    }
  }

  if (!wactive) return;
  #pragma unroll
  for (int mt = 0; mt < 4; ++mt)
    #pragma unroll
    for (int nt = 0; nt < 4; ++nt) {
      int col2 = bn + wn + nt * 16 + lm;
      if (GUARD && col2 >= N) continue;
      float bz = bias[col2];
      #pragma unroll
      for (int i = 0; i < 4; ++i) {
        int rr = bm + wm + mt * 16 + kq * 4 + i;
        float v = acc[mt][nt][i] + bz;
        if (MODE == 1) {
          if (col2 < 16) v = sp(v);          // softplus(delta) once here
          Cb[(size_t)rr * N + col2] = (__bf16)v;
        } else if (MODE == 2) {
          if (col2 < 512) Cb[(size_t)rr * 512 + col2] = (__bf16)v;
          else            Cg[(size_t)rr * 512 + col2 - 512] = (__bf16)silu(v);
        } else {
          Cb[(size_t)rr * N + col2] = (__bf16)v;
        }
      }
    }
}

// ---------------- depthwise causal conv (k=4) + SiLU, bf16 in/out, 8 ch/thread
__global__ void conv_silu(const __bf16* __restrict__ xs,
                          const float* __restrict__ cw,
                          const float* __restrict__ cb,
                          __bf16* __restrict__ xc, int total) {
  int idx = blockIdx.x * 256 + threadIdx.x;   // < R*64
  if (idx >= total) return;
  int d8 = (idx & 63) * 8;
  int bt = idx >> 6;
  int t = bt % SEQC;
  const __bf16* base = xs + (size_t)(bt - t) * 512 + d8;
  float wv[8][4];
  #pragma unroll
  for (int e = 0; e < 8; ++e) {
    float4 wq = *(const float4*)&cw[(d8 + e) * 4];
    wv[e][0] = wq.x; wv[e][1] = wq.y; wv[e][2] = wq.z; wv[e][3] = wq.w;
  }
  float4 b0 = *(const float4*)&cb[d8];
  float4 b1 = *(const float4*)&cb[d8 + 4];
  float acc[8] = {b0.x, b0.y, b0.z, b0.w, b1.x, b1.y, b1.z, b1.w};
  #pragma unroll
  for (int j = 0; j < 4; ++j) {
    int ts = t - 3 + j;
    if (ts >= 0) {
      bf16x8 v = *(const bf16x8*)&base[(size_t)ts * 512];
      #pragma unroll
      for (int e = 0; e < 8; ++e) acc[e] = fmaf(wv[e][j], (float)v[e], acc[e]);
    }
  }
  bf16x8 o;
  #pragma unroll
  for (int e = 0; e < 8; ++e) o[e] = (__bf16)silu(acc[e]);
  *(bf16x8*)&xc[(size_t)bt * 512 + d8] = o;
}

// ---------------- scan phase 1: per-chunk local scan (h=0) -> hend, P (bf16)
// Packed float2 math (v_pk_mul/fma_f32). Chunk NCH-1 is skipped by the
// launcher (its output is never consumed by scan_combine).
__global__ __launch_bounds__(256, 4) void scan_phase1(
    const __bf16* __restrict__ ssm, const float* __restrict__ A_log,
    const __bf16* __restrict__ xc,
    __bf16* __restrict__ hend, __bf16* __restrict__ Pp) {
  __shared__ float sb[SUB * 32];
  __shared__ __bf16 xsb[SUB * 256];
  int b = blockIdx.x, half = blockIdx.y, c = blockIdx.z;
  int tid = threadIdx.x;
  int dg0 = half * 256;
  int d = dg0 + tid;
  floatx2 a2p[8];
  #pragma unroll
  for (int n = 0; n < 8; ++n) {
    a2p[n][0] = -__expf(A_log[d * 16 + 2 * n]) * LOG2E;
    a2p[n][1] = -__expf(A_log[d * 16 + 2 * n + 1]) * LOG2E;
  }
  floatx2 h2[8], S2[8];
  #pragma unroll
  for (int n = 0; n < 8; ++n) { h2[n] = floatx2{0.f, 0.f}; S2[n] = floatx2{0.f, 0.f}; }
  size_t rowbase = (size_t)b * SEQC + c * CT;

  for (int sub = 0; sub < 2; ++sub) {
    int ts0 = sub * SUB;
    __syncthreads();
    for (int i = tid; i < SUB * 8; i += 256) {
      int tt = i >> 3, n4 = (i & 7) * 4;
      bf16x4 v = *(const bf16x4*)&ssm[(rowbase + ts0 + tt) * 32 + n4];
      float4 f = {(float)v[0], (float)v[1], (float)v[2], (float)v[3]};
      *(float4*)&sb[tt * 32 + n4] = f;
    }
    for (int i = tid; i < SUB * 64; i += 256) {
      int tt = i >> 6, j4 = (i & 63) * 4;
      *(bf16x4*)&xsb[tt * 256 + j4] =
          *(const bf16x4*)&xc[(rowbase + ts0 + tt) * 512 + dg0 + j4];
    }
    __syncthreads();
    for (int tt = 0; tt < SUB; ++tt) {
      const floatx2* dv2 = (const floatx2*)&sb[tt * 32];
      floatx2 del2[8], Bv2[8];
      #pragma unroll
      for (int n = 0; n < 8; ++n) { del2[n] = dv2[n]; Bv2[n] = dv2[8 + n]; }
      float xv = (float)xsb[tt * 256 + tid];
      floatx2 xv2 = {xv, xv};
      #pragma unroll
      for (int n = 0; n < 8; ++n) {
        S2[n] += del2[n];
        floatx2 t2 = a2p[n] * del2[n];
        floatx2 e2;
        e2[0] = EXP2F(t2[0]); e2[1] = EXP2F(t2[1]);
        h2[n] = h2[n] * e2 + xv2 * Bv2[n];
      }
    }
  }
  size_t base = ((size_t)(b * NCH + c) * 512 + d) * 16;
  bf16x8 h0, h1, p0, p1;
  #pragma unroll
  for (int n = 0; n < 4; ++n) {
    h0[2 * n] = (__bf16)h2[n][0];     h0[2 * n + 1] = (__bf16)h2[n][1];
    h1[2 * n] = (__bf16)h2[n + 4][0]; h1[2 * n + 1] = (__bf16)h2[n + 4][1];
    p0[2 * n] = (__bf16)EXP2F(a2p[n][0] * S2[n][0]);
    p0[2 * n + 1] = (__bf16)EXP2F(a2p[n][1] * S2[n][1]);
    p1[2 * n] = (__bf16)EXP2F(a2p[n + 4][0] * S2[n + 4][0]);
    p1[2 * n + 1] = (__bf16)EXP2F(a2p[n + 4][1] * S2[n + 4][1]);
  }
  *(bf16x8*)&hend[base] = h0; *(bf16x8*)&hend[base + 8] = h1;
  *(bf16x8*)&Pp[base] = p0;   *(bf16x8*)&Pp[base + 8] = p1;
}

// ---------------- scan phase 2: sequential carry composition (hend -> hin in place)
__global__ __launch_bounds__(64) void scan_combine(
    __bf16* __restrict__ hend, const __bf16* __restrict__ Pp) {
  int b = blockIdx.x;
  int d = blockIdx.y * 64 + threadIdx.x;
  float hp[16] = {};
  for (int c = 0; c < NCH; ++c) {
    size_t base = ((size_t)(b * NCH + c) * 512 + d) * 16;
    bf16x8 he0 = *(const bf16x8*)&hend[base];
    bf16x8 he1 = *(const bf16x8*)&hend[base + 8];
    bf16x8 pp0 = *(const bf16x8*)&Pp[base];
    bf16x8 pp1 = *(const bf16x8*)&Pp[base + 8];
    bf16x8 o0, o1;
    #pragma unroll
    for (int n = 0; n < 8; ++n) {
      o0[n] = (__bf16)hp[n]; o1[n] = (__bf16)hp[n + 8];
      hp[n]     = fmaf((float)pp0[n], hp[n],     (float)he0[n]);
      hp[n + 8] = fmaf((float)pp1[n], hp[n + 8], (float)he1[n]);
    }
    *(bf16x8*)&hend[base] = o0; *(bf16x8*)&hend[base + 8] = o1;
  }
}

// ---------------- scan phase 3: local scan with carry, y, gate -> yc bf16
// Packed float2 math.
__global__ __launch_bounds__(256, 4) void scan_phase3(
    const __bf16* __restrict__ ssm, const float* __restrict__ A_log,
    const float* __restrict__ Dp, const __bf16* __restrict__ xc,
    const __bf16* __restrict__ gate, const __bf16* __restrict__ hin,
    __bf16* __restrict__ yc) {
  __shared__ float sb[SUB * 32];
  __shared__ __bf16 xsb[SUB * 256];
  int b = blockIdx.x, half = blockIdx.y, c = blockIdx.z;
  int tid = threadIdx.x;
  int dg0 = half * 256;
  int d = dg0 + tid;
  floatx2 a2p[8];
  #pragma unroll
  for (int n = 0; n < 8; ++n) {
    a2p[n][0] = -__expf(A_log[d * 16 + 2 * n]) * LOG2E;
    a2p[n][1] = -__expf(A_log[d * 16 + 2 * n + 1]) * LOG2E;
  }
  float Dv = Dp[d];
  floatx2 h2[8];
  {
    size_t base = ((size_t)(b * NCH + c) * 512 + d) * 16;
    bf16x8 h0 = *(const bf16x8*)&hin[base];
    bf16x8 h1 = *(const bf16x8*)&hin[base + 8];
    #pragma unroll
    for (int n = 0; n < 4; ++n) {
      h2[n][0] = (float)h0[2 * n];     h2[n][1] = (float)h0[2 * n + 1];
      h2[n + 4][0] = (float)h1[2 * n]; h2[n + 4][1] = (float)h1[2 * n + 1];
    }
  }
  size_t rowbase = (size_t)b * SEQC + c * CT;

  for (int sub = 0; sub < 2; ++sub) {
    int ts0 = sub * SUB;
    __syncthreads();
    for (int i = tid; i < SUB * 8; i += 256) {
      int tt = i >> 3, n4 = (i & 7) * 4;
      bf16x4 v = *(const bf16x4*)&ssm[(rowbase + ts0 + tt) * 32 + n4];
      float4 f = {(float)v[0], (float)v[1], (float)v[2], (float)v[3]};
      *(float4*)&sb[tt * 32 + n4] = f;
    }
    for (int i = tid; i < SUB * 64; i += 256) {
      int tt = i >> 6, j4 = (i & 63) * 4;
      *(bf16x4*)&xsb[tt * 256 + j4] =
          *(const bf16x4*)&xc[(rowbase + ts0 + tt) * 512 + dg0 + j4];
    }
    __syncthreads();
    for (int tt = 0; tt < SUB; ++tt) {
      const floatx2* dv2 = (const floatx2*)&sb[tt * 32];
      floatx2 del2[8], Bv2[8];
      #pragma unroll
      for (int n = 0; n < 8; ++n) { del2[n] = dv2[n]; Bv2[n] = dv2[8 + n]; }
      float xv = (float)xsb[tt * 256 + tid];
      floatx2 xv2 = {xv, xv};
      floatx2 yq[4];
      #pragma unroll
      for (int q = 0; q < 4; ++q) yq[q] = floatx2{0.f, 0.f};
      #pragma unroll
      for (int n = 0; n < 8; ++n) {
        floatx2 t2 = a2p[n] * del2[n];
        floatx2 e2;
        e2[0] = EXP2F(t2[0]); e2[1] = EXP2F(t2[1]);
        h2[n] = h2[n] * e2 + xv2 * Bv2[n];
        yq[n & 3] = h2[n] * Bv2[n] + yq[n & 3];
      }
      float ysum = ((yq[0][0] + yq[0][1]) + (yq[1][0] + yq[1][1])) +
                   ((yq[2][0] + yq[2][1]) + (yq[3][0] + yq[3][1]));
      xsb[tt * 256 + tid] = (__bf16)fmaf(Dv, xv, ysum);
    }
    __syncthreads();
    for (int i = tid; i < SUB * 64; i += 256) {
      int tt = i >> 6, j4 = (i & 63) * 4;
      size_t o = (rowbase + ts0 + tt) * 512 + dg0 + j4;
      bf16x4 y4 = *(const bf16x4*)&xsb[tt * 256 + j4];
      bf16x4 g4 = *(const bf16x4*)&gate[o];
      bf16x4 r;
      #pragma unroll
      for (int e = 0; e < 4; ++e) r[e] = (__bf16)((float)y4[e] * (float)g4[e]);
      *(bf16x4*)&yc[o] = r;
    }
  }
}

// ---------------- x = LayerNorm(reconstruct(xh,xl) + ob_bf16), re-split; 4 rows/block
__global__ __launch_bounds__(256) void add_ln(
    __bf16* __restrict__ xh, __bf16* __restrict__ xl,
    const __bf16* __restrict__ ob,
    const float* __restrict__ g, const float* __restrict__ bb) {
  int lane = threadIdx.x & 63;
  size_t base = ((size_t)blockIdx.x * 4 + (threadIdx.x >> 6)) * 256;
  bf16x4 h4 = *(const bf16x4*)&xh[base + lane * 4];
  bf16x4 l4 = *(const bf16x4*)&xl[base + lane * 4];
  bf16x4 o4 = *(const bf16x4*)&ob[base + lane * 4];
  float v[4];
  #pragma unroll
  for (int i = 0; i < 4; ++i) v[i] = (float)h4[i] + (float)l4[i] + (float)o4[i];
  float s = v[0] + v[1] + v[2] + v[3];
  #pragma unroll
  for (int off = 32; off > 0; off >>= 1) s += __shfl_down(s, off);
  float mu = __shfl(s, 0) * (1.f / 256.f);
  float var = 0.f;
  #pragma unroll
  for (int i = 0; i < 4; ++i) { float dd = v[i] - mu; var = fmaf(dd, dd, var); }
  #pragma unroll
  for (int off = 32; off > 0; off >>= 1) var += __shfl_down(var, off);
  float r = rsqrtf(__shfl(var, 0) * (1.f / 256.f) + LN_EPSF);
  float4 gv = *(const float4*)&g[lane * 4];
  float4 bv = *(const float4*)&bb[lane * 4];
  float gg[4] = {gv.x, gv.y, gv.z, gv.w};
  float bbv[4] = {bv.x, bv.y, bv.z, bv.w};
  bf16x4 hq, lq;
  #pragma unroll
  for (int i = 0; i < 4; ++i) {
    float o = (v[i] - mu) * r * gg[i] + bbv[i];
    __bf16 hh = (__bf16)o;
    hq[i] = hh;
    lq[i] = (__bf16)(o - (float)hh);
  }
  *(bf16x4*)&xh[base + lane * 4] = hq;
  *(bf16x4*)&xl[base + lane * 4] = lq;
}

// ---------------- fin[b][256] = reconstruct(x) at t=899
__global__ void extract_final(const __bf16* __restrict__ xh,
                              const __bf16* __restrict__ xl,
                              float* __restrict__ fin) {
  int b = blockIdx.x;
  int c = threadIdx.x;
  size_t o = ((size_t)b * SEQC + (SEQC - 1)) * D_MODELC + c;
  fin[(size_t)b * 256 + c] = (float)xh[o] + (float)xl[o];
}

// ---------------- final heads
__global__ __launch_bounds__(128) void heads_kernel(
    const float* __restrict__ fin,
    const float* __restrict__ cnt1_w, const float* __restrict__ cnt1_b,
    const float* __restrict__ cnt2_w, const float* __restrict__ cnt2_b,
    const float* __restrict__ col1_w, const float* __restrict__ col1_b,
    const float* __restrict__ col2_w, const float* __restrict__ col2_b,
    float* __restrict__ out) {
  int b = blockIdx.x;
  int tid = threadIdx.x;
  __shared__ float f[256];
  __shared__ float hc[128];
  __shared__ float hl[128];
  f[tid] = fin[b * 256 + tid];
  f[tid + 128] = fin[b * 256 + tid + 128];
  __syncthreads();
  float s1 = cnt1_b[tid], s2 = col1_b[tid];
  for (int c = 0; c < 256; ++c) {
    float v = f[c];
    s1 = fmaf(v, cnt1_w[c * 128 + tid], s1);
    s2 = fmaf(v, col1_w[c * 128 + tid], s2);
  }
  hc[tid] = fmaxf(s1, 0.f);
  hl[tid] = fmaxf(s2, 0.f);
  __syncthreads();
  if (tid == 0) {
    float t = cnt2_b[0];
    for (int j = 0; j < 128; ++j) t = fmaf(hc[j], cnt2_w[j], t);
    out[b] = fmaxf(t, 0.f);
  }
  if (tid < 10) {
    float t = col2_b[tid];
    for (int j = 0; j < 128; ++j) t = fmaf(hl[j], col2_w[j * 10 + tid], t);
    out[64 + b * 10 + tid] = fmaxf(t, 0.f);
  }
}

extern "C" void kernel_launch(void* const* d_in, const int* in_sizes, int n_in,
                              void* d_out, int out_size, void* d_ws, size_t ws_size,
                              hipStream_t stream) {
  const int*   grid   = (const int*)d_in[0];
  const float* cemb   = (const float*)d_in[1];
  const float* pemb   = (const float*)d_in[2];
  const float* in_w   = (const float*)d_in[3];
  const float* in_b   = (const float*)d_in[4];
  const float* conv_w = (const float*)d_in[5];
  const float* conv_b = (const float*)d_in[6];
  const float* xproj_w= (const float*)d_in[7];
  const float* xproj_b= (const float*)d_in[8];
  const float* A_log  = (const float*)d_in[9];
  const float* Dp     = (const float*)d_in[10];
  const float* out_w  = (const float*)d_in[11];
  const float* out_b  = (const float*)d_in[12];
  const float* ln_g   = (const float*)d_in[13];
  const float* ln_b   = (const float*)d_in[14];
  const float* cnt1_w = (const float*)d_in[15];
  const float* cnt1_b = (const float*)d_in[16];
  const float* cnt2_w = (const float*)d_in[17];
  const float* cnt2_b = (const float*)d_in[18];
  const float* col1_w = (const float*)d_in[19];
  const float* col1_b = (const float*)d_in[20];
  const float* col2_w = (const float*)d_in[21];
  const float* col2_b = (const float*)d_in[22];

  const int R = BATCHC * SEQC;  // 57600
  float* ws = (float*)d_ws;
  size_t off = 0;
  auto alloc = [&](size_t fl) { float* p = ws + off; off += (fl + 63) & ~(size_t)63; return p; };

  float*  fin   = alloc((size_t)BATCHC * 256);
  __bf16* wi    = (__bf16*)alloc((size_t)N_LAYERSC * 1024 * 256 / 2);
  __bf16* wx    = (__bf16*)alloc((size_t)N_LAYERSC * 32 * 512 / 2);
  __bf16* wo    = (__bf16*)alloc((size_t)N_LAYERSC * 256 * 512 / 2);
  __bf16* xh    = (__bf16*)alloc((size_t)R * 256 / 2);
  __bf16* xl    = (__bf16*)alloc((size_t)R * 256 / 2);
  __bf16* xsyc  = (__bf16*)alloc((size_t)R * 512 / 2);   // xs then yc
  float*  gateob= alloc((size_t)R * 512 / 2);            // gate bf16, then ob bf16
  __bf16* xc    = (__bf16*)alloc((size_t)R * 512 / 2);
  __bf16* ssm   = (__bf16*)alloc((size_t)R * 32 / 2);
  __bf16* hend  = (__bf16*)alloc((size_t)BATCHC * NCH * 512 * 16 / 2);
  __bf16* Pp    = (__bf16*)alloc((size_t)BATCHC * NCH * 512 * 16 / 2);
  __bf16* gate  = (__bf16*)gateob;
  __bf16* obb   = (__bf16*)gateob;   // out-proj result (gate dead after phase3)

  // weight prep (once per call)
  wprep<<<dim3(1024, N_LAYERSC), 256, 0, stream>>>(in_w, wi, 256, 1024, 8);
  wprep<<<dim3(64, N_LAYERSC), 256, 0, stream>>>(xproj_w, wx, 512, 32, 9);
  wprep<<<dim3(512, N_LAYERSC), 256, 0, stream>>>(out_w, wo, 512, 256, 9);

  embed_kernel<<<R, 256, 0, stream>>>(grid, cemb, pemb, xh, xl);

  const int NROW = R / 128;   // 450
  for (int l = 0; l < N_LAYERSC; ++l) {
    // in-proj: xs (bf16) + gate = silu(res) (bf16); 1D swizzled grid
    gemm_bf16<2, false><<<NROW * 8, 256, 0, stream>>>(
        xh, wi + (size_t)l * 1024 * 256, in_b + l * 1024,
        xsyc, gate, R, 1024, 256, NROW, 8);
    conv_silu<<<(R * 64 + 255) / 256, 256, 0, stream>>>(
        xsyc, conv_w + (size_t)l * 512 * 4, conv_b + l * 512, xc, R * 64);
    // x-proj: ssm bf16, softplus fused on delta cols (guarded, 1 col tile)
    gemm_bf16<1, true><<<NROW, 256, 0, stream>>>(
        xc, wx + (size_t)l * 32 * 512, xproj_b + l * 32,
        ssm, nullptr, R, 32, 512, NROW, 1);
    // phase1: chunk NCH-1 skipped (output unused by combine)
    scan_phase1<<<dim3(BATCHC, 2, NCH - 1), 256, 0, stream>>>(
        ssm, A_log + (size_t)l * 512 * 16, xc, hend, Pp);
    scan_combine<<<dim3(BATCHC, 8), 64, 0, stream>>>(hend, Pp);
    scan_phase3<<<dim3(BATCHC, 2, NCH), 256, 0, stream>>>(
        ssm, A_log + (size_t)l * 512 * 16, Dp + l * 512, xc, gate, hend, xsyc);
    // out-proj: ob bf16 (overwrites gate region — gate dead after phase3)
    gemm_bf16<3, false><<<NROW * 2, 256, 0, stream>>>(
        xsyc, wo + (size_t)l * 256 * 512, out_b + l * 256,
        obb, nullptr, R, 256, 512, NROW, 2);
    add_ln<<<R / 4, 256, 0, stream>>>(xh, xl, obb, ln_g, ln_b);
  }

  extract_final<<<BATCHC, 256, 0, stream>>>(xh, xl, fin);
  heads_kernel<<<BATCHC, 128, 0, stream>>>(
      fin, cnt1_w, cnt1_b, cnt2_w, cnt2_b, col1_w, col1_b, col2_w, col2_b,
      (float*)d_out);
}

// Round 15
// 1601.963 us; speedup vs baseline: 1.7259x; 1.1979x over previous
//
#include <hip/hip_runtime.h>
#include <cstdint>

#define D_MODELC 256
#define N_LAYERSC 4
#define BATCHC 64
#define SEQC 900
#define NCH 10
#define CT 90
#define SUB 45
#define LN_EPSF 1e-5f
#define LOG2E 1.44269504088896f

typedef __bf16 bf16x8 __attribute__((ext_vector_type(8)));
typedef __bf16 bf16x4 __attribute__((ext_vector_type(4)));
typedef float floatx4 __attribute__((ext_vector_type(4)));
typedef float floatx2 __attribute__((ext_vector_type(2)));

#if defined(__has_builtin)
#if __has_builtin(__builtin_amdgcn_exp2f)
#define EXP2F __builtin_amdgcn_exp2f
#endif
#endif
#ifndef EXP2F
#define EXP2F exp2f
#endif

__device__ inline float sp(float v) { return (v > 20.f) ? v : log1pf(__expf(v)); }
__device__ inline float silu(float v) { return v / (1.f + __expf(-v)); }

// ---------------- weight transpose + cvt: W (L,K,N) -> Wb (L,N,K) bf16
__global__ void wprep(const float* __restrict__ W, __bf16* __restrict__ Wb,
                      int K, int N, int kshift) {
  int l = blockIdx.y;
  int idx = blockIdx.x * 256 + threadIdx.x;
  if (idx >= N * K) return;
  int n = idx >> kshift, k = idx & (K - 1);
  Wb[(size_t)l * N * K + idx] = (__bf16)W[(size_t)l * K * N + (size_t)k * N + n];
}

// ---------------- embed -> split bf16 x
__global__ void embed_kernel(const int* __restrict__ grid,
                             const float* __restrict__ cemb,
                             const float* __restrict__ pemb,
                             __bf16* __restrict__ xh, __bf16* __restrict__ xl) {
  int row = blockIdx.x;
  int c = threadIdx.x;
  int s = row % SEQC;
  int g = grid[row];
  float v = cemb[g * D_MODELC + c] + pemb[s * D_MODELC + c];
  size_t o = (size_t)row * D_MODELC + c;
  __bf16 hh = (__bf16)v;
  xh[o] = hh;
  xl[o] = (__bf16)(v - (float)hh);
}

// ---------------- bf16 MFMA GEMM: C = A(MxK) * W^T(NxK) + bias
// 128x128 tile, 4 waves (2x2), BK=32, single-buffer. XCD supertile swizzle.
// MODE 1: bf16 Cb, softplus cols<16 (x-proj).  MODE 2: in-proj split+silu.
// MODE 3: bf16 Cb plain.  GUARD: compile-time col guards (x-proj only).
#define GLDA 44
template<int MODE, bool GUARD>
__global__ __launch_bounds__(256) void gemm_bf16(
    const __bf16* __restrict__ A, const __bf16* __restrict__ W,
    const float* __restrict__ bias,
    __bf16* __restrict__ Cb, __bf16* __restrict__ Cg,
    int M, int N, int K, int nrow, int ncol) {
  __shared__ __attribute__((aligned(16))) __bf16 As[128 * GLDA];
  __shared__ __attribute__((aligned(16))) __bf16 Bs[128 * GLDA];
  int id = blockIdx.x;
  int row, col;
  {
    int fullsup = (nrow >> 3) * 8 * ncol;
    if (id < fullsup) {
      int per = ncol * 8;
      int s = id / per, r = id % per;
      col = r >> 3;
      row = (s << 3) + (r & 7);
    } else {
      int r = id - fullsup;
      int tr = nrow & 7;
      col = r / tr;
      row = (nrow & ~7) + r % tr;
    }
  }
  int tid = threadIdx.x, lane = tid & 63, w = tid >> 6;
  int bm = row * 128, bn = col * 128;
  int wm = (w >> 1) * 64, wn = (w & 1) * 64;
  int lm = lane & 15, kq = lane >> 4;
  bool wactive = !GUARD || (bn + wn < N);

  floatx4 acc[4][4];
  floatx4 zero = {0.f, 0.f, 0.f, 0.f};
  #pragma unroll
  for (int i = 0; i < 4; ++i)
    #pragma unroll
    for (int j = 0; j < 4; ++j) acc[i][j] = zero;

  int r0 = tid >> 1;          // 0..127
  int kb = (tid & 1) * 16;    // 0 / 16

  for (int k0 = 0; k0 < K; k0 += 32) {
    __syncthreads();
    {
      size_t aoff = (size_t)(bm + r0) * K + k0 + kb;
      *(bf16x8*)&As[r0 * GLDA + kb]     = *(const bf16x8*)&A[aoff];
      *(bf16x8*)&As[r0 * GLDA + kb + 8] = *(const bf16x8*)&A[aoff + 8];
      int nr = bn + r0;
      if (!GUARD || nr < N) {
        size_t boff = (size_t)nr * K + k0 + kb;
        *(bf16x8*)&Bs[r0 * GLDA + kb]     = *(const bf16x8*)&W[boff];
        *(bf16x8*)&Bs[r0 * GLDA + kb + 8] = *(const bf16x8*)&W[boff + 8];
      } else {
        uint4 zu = make_uint4(0, 0, 0, 0);
        *(uint4*)&Bs[r0 * GLDA + kb] = zu;
        *(uint4*)&Bs[r0 * GLDA + kb + 8] = zu;
      }
    }
    __syncthreads();
    if (wactive) {
      bf16x8 fa[4], fb[4];
      #pragma unroll
      for (int mt = 0; mt < 4; ++mt)
        fa[mt] = *(const bf16x8*)&As[(wm + mt * 16 + lm) * GLDA + kq * 8];
      #pragma unroll
      for (int nt = 0; nt < 4; ++nt)
        fb[nt] = *(const bf16x8*)&Bs[(wn + nt * 16 + lm) * GLDA + kq * 8];
      #pragma unroll
      for (int mt = 0; mt < 4; ++mt)
        #pragma unroll
        for (int nt = 0; nt < 4; ++nt)
          acc[mt][nt] = __builtin_amdgcn_mfma_f32_16x16x32_bf16(fa[mt], fb[nt], acc[mt][nt], 0, 0, 0);
    }
  }

  if (!wactive) return;
  #pragma unroll
  for (int mt = 0; mt < 4; ++mt)
    #pragma unroll
    for (int nt = 0; nt < 4; ++nt) {
      int col2 = bn + wn + nt * 16 + lm;
      if (GUARD && col2 >= N) continue;
      float bz = bias[col2];
      #pragma unroll
      for (int i = 0; i < 4; ++i) {
        int rr = bm + wm + mt * 16 + kq * 4 + i;
        float v = acc[mt][nt][i] + bz;
        if (MODE == 1) {
          if (col2 < 16) v = sp(v);          // softplus(delta) once here
          Cb[(size_t)rr * N + col2] = (__bf16)v;
        } else if (MODE == 2) {
          if (col2 < 512) Cb[(size_t)rr * 512 + col2] = (__bf16)v;
          else            Cg[(size_t)rr * 512 + col2 - 512] = (__bf16)silu(v);
        } else {
          Cb[(size_t)rr * N + col2] = (__bf16)v;
        }
      }
    }
}

// ---------------- depthwise causal conv (k=4) + SiLU, sliding window:
// each thread computes 4 consecutive t-rows x 8 channels from a 7-row window.
// 900 % 4 == 0 so row-groups never straddle a sequence boundary.
__global__ __launch_bounds__(256) void conv_silu(
    const __bf16* __restrict__ xs, const float* __restrict__ cw,
    const float* __restrict__ cb, __bf16* __restrict__ xc, int total) {
  int idx = blockIdx.x * 256 + threadIdx.x;   // < R*16
  if (idx >= total) return;
  int d8 = (idx & 63) * 8;
  int g4 = idx >> 6;
  int bt0 = g4 * 4;
  int t0 = bt0 % SEQC;
  const __bf16* base = xs + (size_t)(bt0 - t0) * 512 + d8;  // seq start
  float wv[8][4];
  #pragma unroll
  for (int e = 0; e < 8; ++e) {
    float4 wq = *(const float4*)&cw[(d8 + e) * 4];
    wv[e][0] = wq.x; wv[e][1] = wq.y; wv[e][2] = wq.z; wv[e][3] = wq.w;
  }
  float4 b0 = *(const float4*)&cb[d8];
  float4 b1 = *(const float4*)&cb[d8 + 4];
  float bb[8] = {b0.x, b0.y, b0.z, b0.w, b1.x, b1.y, b1.z, b1.w};
  // window rows t0-3 .. t0+3  (j -> t0-3+j)
  float xw[7][8];
  #pragma unroll
  for (int j = 0; j < 7; ++j) {
    int ts = t0 - 3 + j;
    if (ts >= 0) {
      bf16x8 v = *(const bf16x8*)&base[(size_t)ts * 512];
      #pragma unroll
      for (int e = 0; e < 8; ++e) xw[j][e] = (float)v[e];
    } else {
      #pragma unroll
      for (int e = 0; e < 8; ++e) xw[j][e] = 0.f;
    }
  }
  #pragma unroll
  for (int i = 0; i < 4; ++i) {       // output row t0+i, taps at window i..i+3
    bf16x8 o;
    #pragma unroll
    for (int e = 0; e < 8; ++e) {
      float acc = bb[e];
      #pragma unroll
      for (int j = 0; j < 4; ++j) acc = fmaf(wv[e][j], xw[i + j][e], acc);
      o[e] = (__bf16)silu(acc);
    }
    *(bf16x8*)&xc[(size_t)(bt0 + i) * 512 + d8] = o;
  }
}

// ---------------- scan phase 1: per-chunk local scan (h=0) -> hend, P (bf16)
// Packed float2 math. Chunk NCH-1 skipped by launcher (output unused).
__global__ __launch_bounds__(256, 4) void scan_phase1(
    const __bf16* __restrict__ ssm, const float* __restrict__ A_log,
    const __bf16* __restrict__ xc,
    __bf16* __restrict__ hend, __bf16* __restrict__ Pp) {
  __shared__ float sb[SUB * 32];
  __shared__ __bf16 xsb[SUB * 256];
  int b = blockIdx.x, half = blockIdx.y, c = blockIdx.z;
  int tid = threadIdx.x;
  int dg0 = half * 256;
  int d = dg0 + tid;
  floatx2 a2p[8];
  #pragma unroll
  for (int n = 0; n < 8; ++n) {
    a2p[n][0] = -__expf(A_log[d * 16 + 2 * n]) * LOG2E;
    a2p[n][1] = -__expf(A_log[d * 16 + 2 * n + 1]) * LOG2E;
  }
  floatx2 h2[8], S2[8];
  #pragma unroll
  for (int n = 0; n < 8; ++n) { h2[n] = floatx2{0.f, 0.f}; S2[n] = floatx2{0.f, 0.f}; }
  size_t rowbase = (size_t)b * SEQC + c * CT;

  for (int sub = 0; sub < 2; ++sub) {
    int ts0 = sub * SUB;
    __syncthreads();
    for (int i = tid; i < SUB * 8; i += 256) {
      int tt = i >> 3, n4 = (i & 7) * 4;
      bf16x4 v = *(const bf16x4*)&ssm[(rowbase + ts0 + tt) * 32 + n4];
      float4 f = {(float)v[0], (float)v[1], (float)v[2], (float)v[3]};
      *(float4*)&sb[tt * 32 + n4] = f;
    }
    for (int i = tid; i < SUB * 64; i += 256) {
      int tt = i >> 6, j4 = (i & 63) * 4;
      *(bf16x4*)&xsb[tt * 256 + j4] =
          *(const bf16x4*)&xc[(rowbase + ts0 + tt) * 512 + dg0 + j4];
    }
    __syncthreads();
    for (int tt = 0; tt < SUB; ++tt) {
      const floatx2* dv2 = (const floatx2*)&sb[tt * 32];
      floatx2 del2[8], Bv2[8];
      #pragma unroll
      for (int n = 0; n < 8; ++n) { del2[n] = dv2[n]; Bv2[n] = dv2[8 + n]; }
      float xv = (float)xsb[tt * 256 + tid];
      floatx2 xv2 = {xv, xv};
      #pragma unroll
      for (int n = 0; n < 8; ++n) {
        S2[n] += del2[n];
        floatx2 t2 = a2p[n] * del2[n];
        floatx2 e2;
        e2[0] = EXP2F(t2[0]); e2[1] = EXP2F(t2[1]);
        h2[n] = h2[n] * e2 + xv2 * Bv2[n];
      }
    }
  }
  size_t base = ((size_t)(b * NCH + c) * 512 + d) * 16;
  bf16x8 h0, h1, p0, p1;
  #pragma unroll
  for (int n = 0; n < 4; ++n) {
    h0[2 * n] = (__bf16)h2[n][0];     h0[2 * n + 1] = (__bf16)h2[n][1];
    h1[2 * n] = (__bf16)h2[n + 4][0]; h1[2 * n + 1] = (__bf16)h2[n + 4][1];
    p0[2 * n] = (__bf16)EXP2F(a2p[n][0] * S2[n][0]);
    p0[2 * n + 1] = (__bf16)EXP2F(a2p[n][1] * S2[n][1]);
    p1[2 * n] = (__bf16)EXP2F(a2p[n + 4][0] * S2[n + 4][0]);
    p1[2 * n + 1] = (__bf16)EXP2F(a2p[n + 4][1] * S2[n + 4][1]);
  }
  *(bf16x8*)&hend[base] = h0; *(bf16x8*)&hend[base + 8] = h1;
  *(bf16x8*)&Pp[base] = p0;   *(bf16x8*)&Pp[base + 8] = p1;
}

// ---------------- scan phase 2: sequential carry composition (hend -> hin in place)
__global__ __launch_bounds__(64) void scan_combine(
    __bf16* __restrict__ hend, const __bf16* __restrict__ Pp) {
  int b = blockIdx.x;
  int d = blockIdx.y * 64 + threadIdx.x;
  float hp[16] = {};
  for (int c = 0; c < NCH; ++c) {
    size_t base = ((size_t)(b * NCH + c) * 512 + d) * 16;
    bf16x8 he0 = *(const bf16x8*)&hend[base];
    bf16x8 he1 = *(const bf16x8*)&hend[base + 8];
    bf16x8 pp0 = *(const bf16x8*)&Pp[base];
    bf16x8 pp1 = *(const bf16x8*)&Pp[base + 8];
    bf16x8 o0, o1;
    #pragma unroll
    for (int n = 0; n < 8; ++n) {
      o0[n] = (__bf16)hp[n]; o1[n] = (__bf16)hp[n + 8];
      hp[n]     = fmaf((float)pp0[n], hp[n],     (float)he0[n]);
      hp[n + 8] = fmaf((float)pp1[n], hp[n + 8], (float)he1[n]);
    }
    *(bf16x8*)&hend[base] = o0; *(bf16x8*)&hend[base + 8] = o1;
  }
}

// ---------------- scan phase 3: local scan with carry, y, gate -> yc bf16
// Packed float2 math.
__global__ __launch_bounds__(256, 4) void scan_phase3(
    const __bf16* __restrict__ ssm, const float* __restrict__ A_log,
    const float* __restrict__ Dp, const __bf16* __restrict__ xc,
    const __bf16* __restrict__ gate, const __bf16* __restrict__ hin,
    __bf16* __restrict__ yc) {
  __shared__ float sb[SUB * 32];
  __shared__ __bf16 xsb[SUB * 256];
  int b = blockIdx.x, half = blockIdx.y, c = blockIdx.z;
  int tid = threadIdx.x;
  int dg0 = half * 256;
  int d = dg0 + tid;
  floatx2 a2p[8];
  #pragma unroll
  for (int n = 0; n < 8; ++n) {
    a2p[n][0] = -__expf(A_log[d * 16 + 2 * n]) * LOG2E;
    a2p[n][1] = -__expf(A_log[d * 16 + 2 * n + 1]) * LOG2E;
  }
  float Dv = Dp[d];
  floatx2 h2[8];
  {
    size_t base = ((size_t)(b * NCH + c) * 512 + d) * 16;
    bf16x8 h0 = *(const bf16x8*)&hin[base];
    bf16x8 h1 = *(const bf16x8*)&hin[base + 8];
    #pragma unroll
    for (int n = 0; n < 4; ++n) {
      h2[n][0] = (float)h0[2 * n];     h2[n][1] = (float)h0[2 * n + 1];
      h2[n + 4][0] = (float)h1[2 * n]; h2[n + 4][1] = (float)h1[2 * n + 1];
    }
  }
  size_t rowbase = (size_t)b * SEQC + c * CT;

  for (int sub = 0; sub < 2; ++sub) {
    int ts0 = sub * SUB;
    __syncthreads();
    for (int i = tid; i < SUB * 8; i += 256) {
      int tt = i >> 3, n4 = (i & 7) * 4;
      bf16x4 v = *(const bf16x4*)&ssm[(rowbase + ts0 + tt) * 32 + n4];
      float4 f = {(float)v[0], (float)v[1], (float)v[2], (float)v[3]};
      *(float4*)&sb[tt * 32 + n4] = f;
    }
    for (int i = tid; i < SUB * 64; i += 256) {
      int tt = i >> 6, j4 = (i & 63) * 4;
      *(bf16x4*)&xsb[tt * 256 + j4] =
          *(const bf16x4*)&xc[(rowbase + ts0 + tt) * 512 + dg0 + j4];
    }
    __syncthreads();
    for (int tt = 0; tt < SUB; ++tt) {
      const floatx2* dv2 = (const floatx2*)&sb[tt * 32];
      floatx2 del2[8], Bv2[8];
      #pragma unroll
      for (int n = 0; n < 8; ++n) { del2[n] = dv2[n]; Bv2[n] = dv2[8 + n]; }
      float xv = (float)xsb[tt * 256 + tid];
      floatx2 xv2 = {xv, xv};
      floatx2 yq[4];
      #pragma unroll
      for (int q = 0; q < 4; ++q) yq[q] = floatx2{0.f, 0.f};
      #pragma unroll
      for (int n = 0; n < 8; ++n) {
        floatx2 t2 = a2p[n] * del2[n];
        floatx2 e2;
        e2[0] = EXP2F(t2[0]); e2[1] = EXP2F(t2[1]);
        h2[n] = h2[n] * e2 + xv2 * Bv2[n];
        yq[n & 3] = h2[n] * Bv2[n] + yq[n & 3];
      }
      float ysum = ((yq[0][0] + yq[0][1]) + (yq[1][0] + yq[1][1])) +
                   ((yq[2][0] + yq[2][1]) + (yq[3][0] + yq[3][1]));
      xsb[tt * 256 + tid] = (__bf16)fmaf(Dv, xv, ysum);
    }
    __syncthreads();
    for (int i = tid; i < SUB * 64; i += 256) {
      int tt = i >> 6, j4 = (i & 63) * 4;
      size_t o = (rowbase + ts0 + tt) * 512 + dg0 + j4;
      bf16x4 y4 = *(const bf16x4*)&xsb[tt * 256 + j4];
      bf16x4 g4 = *(const bf16x4*)&gate[o];
      bf16x4 r;
      #pragma unroll
      for (int e = 0; e < 4; ++e) r[e] = (__bf16)((float)y4[e] * (float)g4[e]);
      *(bf16x4*)&yc[o] = r;
    }
  }
}

// ---------------- x = LayerNorm(reconstruct(xh,xl) + ob_bf16), re-split; 4 rows/block
__global__ __launch_bounds__(256) void add_ln(
    __bf16* __restrict__ xh, __bf16* __restrict__ xl,
    const __bf16* __restrict__ ob,
    const float* __restrict__ g, const float* __restrict__ bb) {
  int lane = threadIdx.x & 63;
  size_t base = ((size_t)blockIdx.x * 4 + (threadIdx.x >> 6)) * 256;
  bf16x4 h4 = *(const bf16x4*)&xh[base + lane * 4];
  bf16x4 l4 = *(const bf16x4*)&xl[base + lane * 4];
  bf16x4 o4 = *(const bf16x4*)&ob[base + lane * 4];
  float v[4];
  #pragma unroll
  for (int i = 0; i < 4; ++i) v[i] = (float)h4[i] + (float)l4[i] + (float)o4[i];
  float s = v[0] + v[1] + v[2] + v[3];
  #pragma unroll
  for (int off = 32; off > 0; off >>= 1) s += __shfl_down(s, off);
  float mu = __shfl(s, 0) * (1.f / 256.f);
  float var = 0.f;
  #pragma unroll
  for (int i = 0; i < 4; ++i) { float dd = v[i] - mu; var = fmaf(dd, dd, var); }
  #pragma unroll
  for (int off = 32; off > 0; off >>= 1) var += __shfl_down(var, off);
  float r = rsqrtf(__shfl(var, 0) * (1.f / 256.f) + LN_EPSF);
  float4 gv = *(const float4*)&g[lane * 4];
  float4 bv = *(const float4*)&bb[lane * 4];
  float gg[4] = {gv.x, gv.y, gv.z, gv.w};
  float bbv[4] = {bv.x, bv.y, bv.z, bv.w};
  bf16x4 hq, lq;
  #pragma unroll
  for (int i = 0; i < 4; ++i) {
    float o = (v[i] - mu) * r * gg[i] + bbv[i];
    __bf16 hh = (__bf16)o;
    hq[i] = hh;
    lq[i] = (__bf16)(o - (float)hh);
  }
  *(bf16x4*)&xh[base + lane * 4] = hq;
  *(bf16x4*)&xl[base + lane * 4] = lq;
}

// ---------------- fin[b][256] = reconstruct(x) at t=899
__global__ void extract_final(const __bf16* __restrict__ xh,
                              const __bf16* __restrict__ xl,
                              float* __restrict__ fin) {
  int b = blockIdx.x;
  int c = threadIdx.x;
  size_t o = ((size_t)b * SEQC + (SEQC - 1)) * D_MODELC + c;
  fin[(size_t)b * 256 + c] = (float)xh[o] + (float)xl[o];
}

// ---------------- final heads
__global__ __launch_bounds__(128) void heads_kernel(
    const float* __restrict__ fin,
    const float* __restrict__ cnt1_w, const float* __restrict__ cnt1_b,
    const float* __restrict__ cnt2_w, const float* __restrict__ cnt2_b,
    const float* __restrict__ col1_w, const float* __restrict__ col1_b,
    const float* __restrict__ col2_w, const float* __restrict__ col2_b,
    float* __restrict__ out) {
  int b = blockIdx.x;
  int tid = threadIdx.x;
  __shared__ float f[256];
  __shared__ float hc[128];
  __shared__ float hl[128];
  f[tid] = fin[b * 256 + tid];
  f[tid + 128] = fin[b * 256 + tid + 128];
  __syncthreads();
  float s1 = cnt1_b[tid], s2 = col1_b[tid];
  for (int c = 0; c < 256; ++c) {
    float v = f[c];
    s1 = fmaf(v, cnt1_w[c * 128 + tid], s1);
    s2 = fmaf(v, col1_w[c * 128 + tid], s2);
  }
  hc[tid] = fmaxf(s1, 0.f);
  hl[tid] = fmaxf(s2, 0.f);
  __syncthreads();
  if (tid == 0) {
    float t = cnt2_b[0];
    for (int j = 0; j < 128; ++j) t = fmaf(hc[j], cnt2_w[j], t);
    out[b] = fmaxf(t, 0.f);
  }
  if (tid < 10) {
    float t = col2_b[tid];
    for (int j = 0; j < 128; ++j) t = fmaf(hl[j], col2_w[j * 10 + tid], t);
    out[64 + b * 10 + tid] = fmaxf(t, 0.f);
  }
}

extern "C" void kernel_launch(void* const* d_in, const int* in_sizes, int n_in,
                              void* d_out, int out_size, void* d_ws, size_t ws_size,
                              hipStream_t stream) {
  const int*   grid   = (const int*)d_in[0];
  const float* cemb   = (const float*)d_in[1];
  const float* pemb   = (const float*)d_in[2];
  const float* in_w   = (const float*)d_in[3];
  const float* in_b   = (const float*)d_in[4];
  const float* conv_w = (const float*)d_in[5];
  const float* conv_b = (const float*)d_in[6];
  const float* xproj_w= (const float*)d_in[7];
  const float* xproj_b= (const float*)d_in[8];
  const float* A_log  = (const float*)d_in[9];
  const float* Dp     = (const float*)d_in[10];
  const float* out_w  = (const float*)d_in[11];
  const float* out_b  = (const float*)d_in[12];
  const float* ln_g   = (const float*)d_in[13];
  const float* ln_b   = (const float*)d_in[14];
  const float* cnt1_w = (const float*)d_in[15];
  const float* cnt1_b = (const float*)d_in[16];
  const float* cnt2_w = (const float*)d_in[17];
  const float* cnt2_b = (const float*)d_in[18];
  const float* col1_w = (const float*)d_in[19];
  const float* col1_b = (const float*)d_in[20];
  const float* col2_w = (const float*)d_in[21];
  const float* col2_b = (const float*)d_in[22];

  const int R = BATCHC * SEQC;  // 57600
  float* ws = (float*)d_ws;
  size_t off = 0;
  auto alloc = [&](size_t fl) { float* p = ws + off; off += (fl + 63) & ~(size_t)63; return p; };

  float*  fin   = alloc((size_t)BATCHC * 256);
  __bf16* wi    = (__bf16*)alloc((size_t)N_LAYERSC * 1024 * 256 / 2);
  __bf16* wx    = (__bf16*)alloc((size_t)N_LAYERSC * 32 * 512 / 2);
  __bf16* wo    = (__bf16*)alloc((size_t)N_LAYERSC * 256 * 512 / 2);
  __bf16* xh    = (__bf16*)alloc((size_t)R * 256 / 2);
  __bf16* xl    = (__bf16*)alloc((size_t)R * 256 / 2);
  __bf16* xsyc  = (__bf16*)alloc((size_t)R * 512 / 2);   // xs then yc
  float*  gateob= alloc((size_t)R * 512 / 2);            // gate bf16, then ob bf16
  __bf16* xc    = (__bf16*)alloc((size_t)R * 512 / 2);
  __bf16* ssm   = (__bf16*)alloc((size_t)R * 32 / 2);
  __bf16* hend  = (__bf16*)alloc((size_t)BATCHC * NCH * 512 * 16 / 2);
  __bf16* Pp    = (__bf16*)alloc((size_t)BATCHC * NCH * 512 * 16 / 2);
  __bf16* gate  = (__bf16*)gateob;
  __bf16* obb   = (__bf16*)gateob;   // out-proj result (gate dead after phase3)

  // weight prep (once per call)
  wprep<<<dim3(1024, N_LAYERSC), 256, 0, stream>>>(in_w, wi, 256, 1024, 8);
  wprep<<<dim3(64, N_LAYERSC), 256, 0, stream>>>(xproj_w, wx, 512, 32, 9);
  wprep<<<dim3(512, N_LAYERSC), 256, 0, stream>>>(out_w, wo, 512, 256, 9);

  embed_kernel<<<R, 256, 0, stream>>>(grid, cemb, pemb, xh, xl);

  const int NROW = R / 128;   // 450
  for (int l = 0; l < N_LAYERSC; ++l) {
    // in-proj: xs (bf16) + gate = silu(res) (bf16); 1D swizzled grid
    gemm_bf16<2, false><<<NROW * 8, 256, 0, stream>>>(
        xh, wi + (size_t)l * 1024 * 256, in_b + l * 1024,
        xsyc, gate, R, 1024, 256, NROW, 8);
    conv_silu<<<(R * 16 + 255) / 256, 256, 0, stream>>>(
        xsyc, conv_w + (size_t)l * 512 * 4, conv_b + l * 512, xc, R * 16);
    // x-proj: ssm bf16, softplus fused on delta cols (guarded, 1 col tile)
    gemm_bf16<1, true><<<NROW, 256, 0, stream>>>(
        xc, wx + (size_t)l * 32 * 512, xproj_b + l * 32,
        ssm, nullptr, R, 32, 512, NROW, 1);
    // phase1: chunk NCH-1 skipped (output unused by combine)
    scan_phase1<<<dim3(BATCHC, 2, NCH - 1), 256, 0, stream>>>(
        ssm, A_log + (size_t)l * 512 * 16, xc, hend, Pp);
    scan_combine<<<dim3(BATCHC, 8), 64, 0, stream>>>(hend, Pp);
    scan_phase3<<<dim3(BATCHC, 2, NCH), 256, 0, stream>>>(
        ssm, A_log + (size_t)l * 512 * 16, Dp + l * 512, xc, gate, hend, xsyc);
    // out-proj: ob bf16 (overwrites gate region — gate dead after phase3)
    gemm_bf16<3, false><<<NROW * 2, 256, 0, stream>>>(
        xsyc, wo + (size_t)l * 256 * 512, out_b + l * 256,
        obb, nullptr, R, 256, 512, NROW, 2);
    add_ln<<<R / 4, 256, 0, stream>>>(xh, xl, obb, ln_g, ln_b);
  }

  extract_final<<<BATCHC, 256, 0, stream>>>(xh, xl, fin);
  heads_kernel<<<BATCHC, 128, 0, stream>>>(
      fin, cnt1_w, cnt1_b, cnt2_w, cnt2_b, col1_w, col1_b, col2_w, col2_b,
      (float*)d_out);
}

// Round 16
// 1543.880 us; speedup vs baseline: 1.7908x; 1.0376x over previous
//
#include <hip/hip_runtime.h>
#include <cstdint>

#define D_MODELC 256
#define N_LAYERSC 4
#define BATCHC 64
#define SEQC 900
#define NCH 10
#define CT 90
#define SUB 45
#define LN_EPSF 1e-5f
#define LOG2E 1.44269504088896f

typedef __bf16 bf16x8 __attribute__((ext_vector_type(8)));
typedef __bf16 bf16x4 __attribute__((ext_vector_type(4)));
typedef float floatx4 __attribute__((ext_vector_type(4)));
typedef float floatx2 __attribute__((ext_vector_type(2)));

#if defined(__has_builtin)
#if __has_builtin(__builtin_amdgcn_exp2f)
#define EXP2F __builtin_amdgcn_exp2f
#endif
#endif
#ifndef EXP2F
#define EXP2F exp2f
#endif

__device__ inline float sp(float v) { return (v > 20.f) ? v : log1pf(__expf(v)); }
__device__ inline float silu(float v) { return v / (1.f + __expf(-v)); }

// ---------------- weight transpose + cvt: W (L,K,N) -> Wb (L,N,K) bf16
__global__ void wprep(const float* __restrict__ W, __bf16* __restrict__ Wb,
                      int K, int N, int kshift) {
  int l = blockIdx.y;
  int idx = blockIdx.x * 256 + threadIdx.x;
  if (idx >= N * K) return;
  int n = idx >> kshift, k = idx & (K - 1);
  Wb[(size_t)l * N * K + idx] = (__bf16)W[(size_t)l * K * N + (size_t)k * N + n];
}

// ---------------- embed -> split bf16 x
__global__ void embed_kernel(const int* __restrict__ grid,
                             const float* __restrict__ cemb,
                             const float* __restrict__ pemb,
                             __bf16* __restrict__ xh, __bf16* __restrict__ xl) {
  int row = blockIdx.x;
  int c = threadIdx.x;
  int s = row % SEQC;
  int g = grid[row];
  float v = cemb[g * D_MODELC + c] + pemb[s * D_MODELC + c];
  size_t o = (size_t)row * D_MODELC + c;
  __bf16 hh = (__bf16)v;
  xh[o] = hh;
  xl[o] = (__bf16)(v - (float)hh);
}

// ---------------- bf16 MFMA GEMM: C = A(MxK) * W^T(NxK) + bias
// 128x128 tile, 4 waves (2x2), BK=32, single-buffer. XCD supertile swizzle.
// MODE 1: bf16 Cb, softplus cols<16 (x-proj).  MODE 2: in-proj split+silu.
// MODE 3: bf16 Cb plain.  GUARD: compile-time col guards (x-proj only).
#define GLDA 44
template<int MODE, bool GUARD>
__global__ __launch_bounds__(256) void gemm_bf16(
    const __bf16* __restrict__ A, const __bf16* __restrict__ W,
    const float* __restrict__ bias,
    __bf16* __restrict__ Cb, __bf16* __restrict__ Cg,
    int M, int N, int K, int nrow, int ncol) {
  __shared__ __attribute__((aligned(16))) __bf16 As[128 * GLDA];
  __shared__ __attribute__((aligned(16))) __bf16 Bs[128 * GLDA];
  int id = blockIdx.x;
  int row, col;
  {
    int fullsup = (nrow >> 3) * 8 * ncol;
    if (id < fullsup) {
      int per = ncol * 8;
      int s = id / per, r = id % per;
      col = r >> 3;
      row = (s << 3) + (r & 7);
    } else {
      int r = id - fullsup;
      int tr = nrow & 7;
      col = r / tr;
      row = (nrow & ~7) + r % tr;
    }
  }
  int tid = threadIdx.x, lane = tid & 63, w = tid >> 6;
  int bm = row * 128, bn = col * 128;
  int wm = (w >> 1) * 64, wn = (w & 1) * 64;
  int lm = lane & 15, kq = lane >> 4;
  bool wactive = !GUARD || (bn + wn < N);

  floatx4 acc[4][4];
  floatx4 zero = {0.f, 0.f, 0.f, 0.f};
  #pragma unroll
  for (int i = 0; i < 4; ++i)
    #pragma unroll
    for (int j = 0; j < 4; ++j) acc[i][j] = zero;

  int r0 = tid >> 1;          // 0..127
  int kb = (tid & 1) * 16;    // 0 / 16

  for (int k0 = 0; k0 < K; k0 += 32) {
    __syncthreads();
    {
      size_t aoff = (size_t)(bm + r0) * K + k0 + kb;
      *(bf16x8*)&As[r0 * GLDA + kb]     = *(const bf16x8*)&A[aoff];
      *(bf16x8*)&As[r0 * GLDA + kb + 8] = *(const bf16x8*)&A[aoff + 8];
      int nr = bn + r0;
      if (!GUARD || nr < N) {
        size_t boff = (size_t)nr * K + k0 + kb;
        *(bf16x8*)&Bs[r0 * GLDA + kb]     = *(const bf16x8*)&W[boff];
        *(bf16x8*)&Bs[r0 * GLDA + kb + 8] = *(const bf16x8*)&W[boff + 8];
      } else {
        uint4 zu = make_uint4(0, 0, 0, 0);
        *(uint4*)&Bs[r0 * GLDA + kb] = zu;
        *(uint4*)&Bs[r0 * GLDA + kb + 8] = zu;
      }
    }
    __syncthreads();
    if (wactive) {
      bf16x8 fa[4], fb[4];
      #pragma unroll
      for (int mt = 0; mt < 4; ++mt)
        fa[mt] = *(const bf16x8*)&As[(wm + mt * 16 + lm) * GLDA + kq * 8];
      #pragma unroll
      for (int nt = 0; nt < 4; ++nt)
        fb[nt] = *(const bf16x8*)&Bs[(wn + nt * 16 + lm) * GLDA + kq * 8];
      #pragma unroll
      for (int mt = 0; mt < 4; ++mt)
        #pragma unroll
        for (int nt = 0; nt < 4; ++nt)
          acc[mt][nt] = __builtin_amdgcn_mfma_f32_16x16x32_bf16(fa[mt], fb[nt], acc[mt][nt], 0, 0, 0);
    }
  }

  if (!wactive) return;
  #pragma unroll
  for (int mt = 0; mt < 4; ++mt)
    #pragma unroll
    for (int nt = 0; nt < 4; ++nt) {
      int col2 = bn + wn + nt * 16 + lm;
      if (GUARD && col2 >= N) continue;
      float bz = bias[col2];
      #pragma unroll
      for (int i = 0; i < 4; ++i) {
        int rr = bm + wm + mt * 16 + kq * 4 + i;
        float v = acc[mt][nt][i] + bz;
        if (MODE == 1) {
          if (col2 < 16) v = sp(v);          // softplus(delta) once here
          Cb[(size_t)rr * N + col2] = (__bf16)v;
        } else if (MODE == 2) {
          if (col2 < 512) Cb[(size_t)rr * 512 + col2] = (__bf16)v;
          else            Cg[(size_t)rr * 512 + col2 - 512] = (__bf16)silu(v);
        } else {
          Cb[(size_t)rr * N + col2] = (__bf16)v;
        }
      }
    }
}

// ---------------- depthwise causal conv (k=4) + SiLU, sliding window, 4 rows/thread
__global__ __launch_bounds__(256) void conv_silu(
    const __bf16* __restrict__ xs, const float* __restrict__ cw,
    const float* __restrict__ cb, __bf16* __restrict__ xc, int total) {
  int idx = blockIdx.x * 256 + threadIdx.x;   // < R*16
  if (idx >= total) return;
  int d8 = (idx & 63) * 8;
  int g4 = idx >> 6;
  int bt0 = g4 * 4;
  int t0 = bt0 % SEQC;
  const __bf16* base = xs + (size_t)(bt0 - t0) * 512 + d8;  // seq start
  float wv[8][4];
  #pragma unroll
  for (int e = 0; e < 8; ++e) {
    float4 wq = *(const float4*)&cw[(d8 + e) * 4];
    wv[e][0] = wq.x; wv[e][1] = wq.y; wv[e][2] = wq.z; wv[e][3] = wq.w;
  }
  float4 b0 = *(const float4*)&cb[d8];
  float4 b1 = *(const float4*)&cb[d8 + 4];
  float bb[8] = {b0.x, b0.y, b0.z, b0.w, b1.x, b1.y, b1.z, b1.w};
  float xw[7][8];
  #pragma unroll
  for (int j = 0; j < 7; ++j) {
    int ts = t0 - 3 + j;
    if (ts >= 0) {
      bf16x8 v = *(const bf16x8*)&base[(size_t)ts * 512];
      #pragma unroll
      for (int e = 0; e < 8; ++e) xw[j][e] = (float)v[e];
    } else {
      #pragma unroll
      for (int e = 0; e < 8; ++e) xw[j][e] = 0.f;
    }
  }
  #pragma unroll
  for (int i = 0; i < 4; ++i) {
    bf16x8 o;
    #pragma unroll
    for (int e = 0; e < 8; ++e) {
      float acc = bb[e];
      #pragma unroll
      for (int j = 0; j < 4; ++j) acc = fmaf(wv[e][j], xw[i + j][e], acc);
      o[e] = (__bf16)silu(acc);
    }
    *(bf16x8*)&xc[(size_t)(bt0 + i) * 512 + d8] = o;
  }
}

// ---------------- scan phase 1: per-chunk local scan (h=0) -> hend, P (bf16)
// Register-pipelined t-loop: next step's del/B (LDS) + xv (global) prefetched
// while computing the current step. No xsb staging — xv read is coalesced.
__global__ __launch_bounds__(256, 4) void scan_phase1(
    const __bf16* __restrict__ ssm, const float* __restrict__ A_log,
    const __bf16* __restrict__ xc,
    __bf16* __restrict__ hend, __bf16* __restrict__ Pp) {
  __shared__ float sb[SUB * 32];
  int b = blockIdx.x, half = blockIdx.y, c = blockIdx.z;
  int tid = threadIdx.x;
  int dg0 = half * 256;
  int d = dg0 + tid;
  floatx2 a2p[8];
  #pragma unroll
  for (int n = 0; n < 8; ++n) {
    a2p[n][0] = -__expf(A_log[d * 16 + 2 * n]) * LOG2E;
    a2p[n][1] = -__expf(A_log[d * 16 + 2 * n + 1]) * LOG2E;
  }
  floatx2 h2[8], S2[8];
  #pragma unroll
  for (int n = 0; n < 8; ++n) { h2[n] = floatx2{0.f, 0.f}; S2[n] = floatx2{0.f, 0.f}; }
  size_t rowbase = (size_t)b * SEQC + c * CT;

  floatx2 dA[8], BA[8], dB[8], BB[8];
  float xA, xB;
  auto loadt = [&](int ts0, int tt, floatx2* del, floatx2* Bv, float& xv) {
    const floatx2* p = (const floatx2*)&sb[tt * 32];
    #pragma unroll
    for (int n = 0; n < 8; ++n) { del[n] = p[n]; Bv[n] = p[8 + n]; }
    xv = (float)xc[(rowbase + ts0 + tt) * 512 + d];
  };
  auto stept = [&](floatx2* del, floatx2* Bv, float xv) {
    floatx2 xv2 = {xv, xv};
    #pragma unroll
    for (int n = 0; n < 8; ++n) {
      S2[n] += del[n];
      floatx2 t2 = a2p[n] * del[n];
      floatx2 e2;
      e2[0] = EXP2F(t2[0]); e2[1] = EXP2F(t2[1]);
      h2[n] = h2[n] * e2 + xv2 * Bv[n];
    }
  };

  for (int sub = 0; sub < 2; ++sub) {
    int ts0 = sub * SUB;
    __syncthreads();
    for (int i = tid; i < SUB * 8; i += 256) {
      int tt = i >> 3, n4 = (i & 7) * 4;
      bf16x4 v = *(const bf16x4*)&ssm[(rowbase + ts0 + tt) * 32 + n4];
      float4 f = {(float)v[0], (float)v[1], (float)v[2], (float)v[3]};
      *(float4*)&sb[tt * 32 + n4] = f;
    }
    __syncthreads();
    loadt(ts0, 0, dA, BA, xA);
    for (int tt = 0; tt < SUB - 1; tt += 2) {
      loadt(ts0, tt + 1, dB, BB, xB);
      stept(dA, BA, xA);
      if (tt + 2 < SUB) loadt(ts0, tt + 2, dA, BA, xA);
      stept(dB, BB, xB);
    }
    stept(dA, BA, xA);   // SUB odd: last step
  }
  size_t base = ((size_t)(b * NCH + c) * 512 + d) * 16;
  bf16x8 h0, h1, p0, p1;
  #pragma unroll
  for (int n = 0; n < 4; ++n) {
    h0[2 * n] = (__bf16)h2[n][0];     h0[2 * n + 1] = (__bf16)h2[n][1];
    h1[2 * n] = (__bf16)h2[n + 4][0]; h1[2 * n + 1] = (__bf16)h2[n + 4][1];
    p0[2 * n] = (__bf16)EXP2F(a2p[n][0] * S2[n][0]);
    p0[2 * n + 1] = (__bf16)EXP2F(a2p[n][1] * S2[n][1]);
    p1[2 * n] = (__bf16)EXP2F(a2p[n + 4][0] * S2[n + 4][0]);
    p1[2 * n + 1] = (__bf16)EXP2F(a2p[n + 4][1] * S2[n + 4][1]);
  }
  *(bf16x8*)&hend[base] = h0; *(bf16x8*)&hend[base + 8] = h1;
  *(bf16x8*)&Pp[base] = p0;   *(bf16x8*)&Pp[base + 8] = p1;
}

// ---------------- scan phase 2: sequential carry composition (hend -> hin in place)
__global__ __launch_bounds__(64) void scan_combine(
    __bf16* __restrict__ hend, const __bf16* __restrict__ Pp) {
  int b = blockIdx.x;
  int d = blockIdx.y * 64 + threadIdx.x;
  float hp[16] = {};
  for (int c = 0; c < NCH; ++c) {
    size_t base = ((size_t)(b * NCH + c) * 512 + d) * 16;
    bf16x8 he0 = *(const bf16x8*)&hend[base];
    bf16x8 he1 = *(const bf16x8*)&hend[base + 8];
    bf16x8 pp0 = *(const bf16x8*)&Pp[base];
    bf16x8 pp1 = *(const bf16x8*)&Pp[base + 8];
    bf16x8 o0, o1;
    #pragma unroll
    for (int n = 0; n < 8; ++n) {
      o0[n] = (__bf16)hp[n]; o1[n] = (__bf16)hp[n + 8];
      hp[n]     = fmaf((float)pp0[n], hp[n],     (float)he0[n]);
      hp[n + 8] = fmaf((float)pp1[n], hp[n + 8], (float)he1[n]);
    }
    *(bf16x8*)&hend[base] = o0; *(bf16x8*)&hend[base + 8] = o1;
  }
}

// ---------------- scan phase 3: local scan with carry, y, gate -> yc bf16
// Register-pipelined t-loop; direct global xv/gate reads and y store.
__global__ __launch_bounds__(256, 4) void scan_phase3(
    const __bf16* __restrict__ ssm, const float* __restrict__ A_log,
    const float* __restrict__ Dp, const __bf16* __restrict__ xc,
    const __bf16* __restrict__ gate, const __bf16* __restrict__ hin,
    __bf16* __restrict__ yc) {
  __shared__ float sb[SUB * 32];
  int b = blockIdx.x, half = blockIdx.y, c = blockIdx.z;
  int tid = threadIdx.x;
  int dg0 = half * 256;
  int d = dg0 + tid;
  floatx2 a2p[8];
  #pragma unroll
  for (int n = 0; n < 8; ++n) {
    a2p[n][0] = -__expf(A_log[d * 16 + 2 * n]) * LOG2E;
    a2p[n][1] = -__expf(A_log[d * 16 + 2 * n + 1]) * LOG2E;
  }
  float Dv = Dp[d];
  floatx2 h2[8];
  {
    size_t base = ((size_t)(b * NCH + c) * 512 + d) * 16;
    bf16x8 h0 = *(const bf16x8*)&hin[base];
    bf16x8 h1 = *(const bf16x8*)&hin[base + 8];
    #pragma unroll
    for (int n = 0; n < 4; ++n) {
      h2[n][0] = (float)h0[2 * n];     h2[n][1] = (float)h0[2 * n + 1];
      h2[n + 4][0] = (float)h1[2 * n]; h2[n + 4][1] = (float)h1[2 * n + 1];
    }
  }
  size_t rowbase = (size_t)b * SEQC + c * CT;

  floatx2 dA[8], BA[8], dB[8], BB[8];
  float xA, xB;
  auto loadt = [&](int ts0, int tt, floatx2* del, floatx2* Bv, float& xv) {
    const floatx2* p = (const floatx2*)&sb[tt * 32];
    #pragma unroll
    for (int n = 0; n < 8; ++n) { del[n] = p[n]; Bv[n] = p[8 + n]; }
    xv = (float)xc[(rowbase + ts0 + tt) * 512 + d];
  };
  auto stept = [&](int ts0, int tt, floatx2* del, floatx2* Bv, float xv) {
    floatx2 xv2 = {xv, xv};
    floatx2 yq0 = {0.f, 0.f}, yq1 = {0.f, 0.f}, yq2 = {0.f, 0.f}, yq3 = {0.f, 0.f};
    #pragma unroll
    for (int n = 0; n < 8; ++n) {
      floatx2 t2 = a2p[n] * del[n];
      floatx2 e2;
      e2[0] = EXP2F(t2[0]); e2[1] = EXP2F(t2[1]);
      h2[n] = h2[n] * e2 + xv2 * Bv[n];
      if ((n & 3) == 0) yq0 = h2[n] * Bv[n] + yq0;
      else if ((n & 3) == 1) yq1 = h2[n] * Bv[n] + yq1;
      else if ((n & 3) == 2) yq2 = h2[n] * Bv[n] + yq2;
      else yq3 = h2[n] * Bv[n] + yq3;
    }
    float ysum = ((yq0[0] + yq0[1]) + (yq1[0] + yq1[1])) +
                 ((yq2[0] + yq2[1]) + (yq3[0] + yq3[1]));
    float y = fmaf(Dv, xv, ysum);
    size_t o = (rowbase + ts0 + tt) * 512 + d;
    float g = (float)gate[o];
    yc[o] = (__bf16)(y * g);
  };

  for (int sub = 0; sub < 2; ++sub) {
    int ts0 = sub * SUB;
    __syncthreads();
    for (int i = tid; i < SUB * 8; i += 256) {
      int tt = i >> 3, n4 = (i & 7) * 4;
      bf16x4 v = *(const bf16x4*)&ssm[(rowbase + ts0 + tt) * 32 + n4];
      float4 f = {(float)v[0], (float)v[1], (float)v[2], (float)v[3]};
      *(float4*)&sb[tt * 32 + n4] = f;
    }
    __syncthreads();
    loadt(ts0, 0, dA, BA, xA);
    for (int tt = 0; tt < SUB - 1; tt += 2) {
      loadt(ts0, tt + 1, dB, BB, xB);
      stept(ts0, tt, dA, BA, xA);
      if (tt + 2 < SUB) loadt(ts0, tt + 2, dA, BA, xA);
      stept(ts0, tt + 1, dB, BB, xB);
    }
    stept(ts0, SUB - 1, dA, BA, xA);   // SUB odd: last step
  }
}

// ---------------- x = LayerNorm(reconstruct(xh,xl) + ob_bf16), re-split; 4 rows/block
__global__ __launch_bounds__(256) void add_ln(
    __bf16* __restrict__ xh, __bf16* __restrict__ xl,
    const __bf16* __restrict__ ob,
    const float* __restrict__ g, const float* __restrict__ bb) {
  int lane = threadIdx.x & 63;
  size_t base = ((size_t)blockIdx.x * 4 + (threadIdx.x >> 6)) * 256;
  bf16x4 h4 = *(const bf16x4*)&xh[base + lane * 4];
  bf16x4 l4 = *(const bf16x4*)&xl[base + lane * 4];
  bf16x4 o4 = *(const bf16x4*)&ob[base + lane * 4];
  float v[4];
  #pragma unroll
  for (int i = 0; i < 4; ++i) v[i] = (float)h4[i] + (float)l4[i] + (float)o4[i];
  float s = v[0] + v[1] + v[2] + v[3];
  #pragma unroll
  for (int off = 32; off > 0; off >>= 1) s += __shfl_down(s, off);
  float mu = __shfl(s, 0) * (1.f / 256.f);
  float var = 0.f;
  #pragma unroll
  for (int i = 0; i < 4; ++i) { float dd = v[i] - mu; var = fmaf(dd, dd, var); }
  #pragma unroll
  for (int off = 32; off > 0; off >>= 1) var += __shfl_down(var, off);
  float r = rsqrtf(__shfl(var, 0) * (1.f / 256.f) + LN_EPSF);
  float4 gv = *(const float4*)&g[lane * 4];
  float4 bv = *(const float4*)&bb[lane * 4];
  float gg[4] = {gv.x, gv.y, gv.z, gv.w};
  float bbv[4] = {bv.x, bv.y, bv.z, bv.w};
  bf16x4 hq, lq;
  #pragma unroll
  for (int i = 0; i < 4; ++i) {
    float o = (v[i] - mu) * r * gg[i] + bbv[i];
    __bf16 hh = (__bf16)o;
    hq[i] = hh;
    lq[i] = (__bf16)(o - (float)hh);
  }
  *(bf16x4*)&xh[base + lane * 4] = hq;
  *(bf16x4*)&xl[base + lane * 4] = lq;
}

// ---------------- fin[b][256] = reconstruct(x) at t=899
__global__ void extract_final(const __bf16* __restrict__ xh,
                              const __bf16* __restrict__ xl,
                              float* __restrict__ fin) {
  int b = blockIdx.x;
  int c = threadIdx.x;
  size_t o = ((size_t)b * SEQC + (SEQC - 1)) * D_MODELC + c;
  fin[(size_t)b * 256 + c] = (float)xh[o] + (float)xl[o];
}

// ---------------- final heads
__global__ __launch_bounds__(128) void heads_kernel(
    const float* __restrict__ fin,
    const float* __restrict__ cnt1_w, const float* __restrict__ cnt1_b,
    const float* __restrict__ cnt2_w, const float* __restrict__ cnt2_b,
    const float* __restrict__ col1_w, const float* __restrict__ col1_b,
    const float* __restrict__ col2_w, const float* __restrict__ col2_b,
    float* __restrict__ out) {
  int b = blockIdx.x;
  int tid = threadIdx.x;
  __shared__ float f[256];
  __shared__ float hc[128];
  __shared__ float hl[128];
  f[tid] = fin[b * 256 + tid];
  f[tid + 128] = fin[b * 256 + tid + 128];
  __syncthreads();
  float s1 = cnt1_b[tid], s2 = col1_b[tid];
  for (int c = 0; c < 256; ++c) {
    float v = f[c];
    s1 = fmaf(v, cnt1_w[c * 128 + tid], s1);
    s2 = fmaf(v, col1_w[c * 128 + tid], s2);
  }
  hc[tid] = fmaxf(s1, 0.f);
  hl[tid] = fmaxf(s2, 0.f);
  __syncthreads();
  if (tid == 0) {
    float t = cnt2_b[0];
    for (int j = 0; j < 128; ++j) t = fmaf(hc[j], cnt2_w[j], t);
    out[b] = fmaxf(t, 0.f);
  }
  if (tid < 10) {
    float t = col2_b[tid];
    for (int j = 0; j < 128; ++j) t = fmaf(hl[j], col2_w[j * 10 + tid], t);
    out[64 + b * 10 + tid] = fmaxf(t, 0.f);
  }
}

extern "C" void kernel_launch(void* const* d_in, const int* in_sizes, int n_in,
                              void* d_out, int out_size, void* d_ws, size_t ws_size,
                              hipStream_t stream) {
  const int*   grid   = (const int*)d_in[0];
  const float* cemb   = (const float*)d_in[1];
  const float* pemb   = (const float*)d_in[2];
  const float* in_w   = (const float*)d_in[3];
  const float* in_b   = (const float*)d_in[4];
  const float* conv_w = (const float*)d_in[5];
  const float* conv_b = (const float*)d_in[6];
  const float* xproj_w= (const float*)d_in[7];
  const float* xproj_b= (const float*)d_in[8];
  const float* A_log  = (const float*)d_in[9];
  const float* Dp     = (const float*)d_in[10];
  const float* out_w  = (const float*)d_in[11];
  const float* out_b  = (const float*)d_in[12];
  const float* ln_g   = (const float*)d_in[13];
  const float* ln_b   = (const float*)d_in[14];
  const float* cnt1_w = (const float*)d_in[15];
  const float* cnt1_b = (const float*)d_in[16];
  const float* cnt2_w = (const float*)d_in[17];
  const float* cnt2_b = (const float*)d_in[18];
  const float* col1_w = (const float*)d_in[19];
  const float* col1_b = (const float*)d_in[20];
  const float* col2_w = (const float*)d_in[21];
  const float* col2_b = (const float*)d_in[22];

  const int R = BATCHC * SEQC;  // 57600
  float* ws = (float*)d_ws;
  size_t off = 0;
  auto alloc = [&](size_t fl) { float* p = ws + off; off += (fl + 63) & ~(size_t)63; return p; };

  float*  fin   = alloc((size_t)BATCHC * 256);
  __bf16* wi    = (__bf16*)alloc((size_t)N_LAYERSC * 1024 * 256 / 2);
  __bf16* wx    = (__bf16*)alloc((size_t)N_LAYERSC * 32 * 512 / 2);
  __bf16* wo    = (__bf16*)alloc((size_t)N_LAYERSC * 256 * 512 / 2);
  __bf16* xh    = (__bf16*)alloc((size_t)R * 256 / 2);
  __bf16* xl    = (__bf16*)alloc((size_t)R * 256 / 2);
  __bf16* xsyc  = (__bf16*)alloc((size_t)R * 512 / 2);   // xs then yc
  float*  gateob= alloc((size_t)R * 512 / 2);            // gate bf16, then ob bf16
  __bf16* xc    = (__bf16*)alloc((size_t)R * 512 / 2);
  __bf16* ssm   = (__bf16*)alloc((size_t)R * 32 / 2);
  __bf16* hend  = (__bf16*)alloc((size_t)BATCHC * NCH * 512 * 16 / 2);
  __bf16* Pp    = (__bf16*)alloc((size_t)BATCHC * NCH * 512 * 16 / 2);
  __bf16* gate  = (__bf16*)gateob;
  __bf16* obb   = (__bf16*)gateob;   // out-proj result (gate dead after phase3)

  // weight prep (once per call)
  wprep<<<dim3(1024, N_LAYERSC), 256, 0, stream>>>(in_w, wi, 256, 1024, 8);
  wprep<<<dim3(64, N_LAYERSC), 256, 0, stream>>>(xproj_w, wx, 512, 32, 9);
  wprep<<<dim3(512, N_LAYERSC), 256, 0, stream>>>(out_w, wo, 512, 256, 9);

  embed_kernel<<<R, 256, 0, stream>>>(grid, cemb, pemb, xh, xl);

  const int NROW = R / 128;   // 450
  for (int l = 0; l < N_LAYERSC; ++l) {
    // in-proj: xs (bf16) + gate = silu(res) (bf16); 1D swizzled grid
    gemm_bf16<2, false><<<NROW * 8, 256, 0, stream>>>(
        xh, wi + (size_t)l * 1024 * 256, in_b + l * 1024,
        xsyc, gate, R, 1024, 256, NROW, 8);
    conv_silu<<<(R * 16 + 255) / 256, 256, 0, stream>>>(
        xsyc, conv_w + (size_t)l * 512 * 4, conv_b + l * 512, xc, R * 16);
    // x-proj: ssm bf16, softplus fused on delta cols (guarded, 1 col tile)
    gemm_bf16<1, true><<<NROW, 256, 0, stream>>>(
        xc, wx + (size_t)l * 32 * 512, xproj_b + l * 32,
        ssm, nullptr, R, 32, 512, NROW, 1);
    // phase1: chunk NCH-1 skipped (output unused by combine)
    scan_phase1<<<dim3(BATCHC, 2, NCH - 1), 256, 0, stream>>>(
        ssm, A_log + (size_t)l * 512 * 16, xc, hend, Pp);
    scan_combine<<<dim3(BATCHC, 8), 64, 0, stream>>>(hend, Pp);
    scan_phase3<<<dim3(BATCHC, 2, NCH), 256, 0, stream>>>(
        ssm, A_log + (size_t)l * 512 * 16, Dp + l * 512, xc, gate, hend, xsyc);
    // out-proj: ob bf16 (overwrites gate region — gate dead after phase3)
    gemm_bf16<3, false><<<NROW * 2, 256, 0, stream>>>(
        xsyc, wo + (size_t)l * 256 * 512, out_b + l * 256,
        obb, nullptr, R, 256, 512, NROW, 2);
    add_ln<<<R / 4, 256, 0, stream>>>(xh, xl, obb, ln_g, ln_b);
  }

  extract_final<<<BATCHC, 256, 0, stream>>>(xh, xl, fin);
  heads_kernel<<<BATCHC, 128, 0, stream>>>(
      fin, cnt1_w, cnt1_b, cnt2_w, cnt2_b, col1_w, col1_b, col2_w, col2_b,
      (float*)d_out);
}

// Round 17
// 1543.538 us; speedup vs baseline: 1.7912x; 1.0002x over previous
//
#include <hip/hip_runtime.h>
#include <cstdint>

#define D_MODELC 256
#define N_LAYERSC 4
#define BATCHC 64
#define SEQC 900
#define NCH 10
#define CT 90
#define SUB 45
#define LN_EPSF 1e-5f
#define LOG2E 1.44269504088896f

typedef __bf16 bf16x8 __attribute__((ext_vector_type(8)));
typedef __bf16 bf16x4 __attribute__((ext_vector_type(4)));
typedef float floatx4 __attribute__((ext_vector_type(4)));
typedef float floatx2 __attribute__((ext_vector_type(2)));

#if defined(__has_builtin)
#if __has_builtin(__builtin_amdgcn_exp2f)
#define EXP2F __builtin_amdgcn_exp2f
#endif
#endif
#ifndef EXP2F
#define EXP2F exp2f
#endif

__device__ inline float sp(float v) { return (v > 20.f) ? v : log1pf(__expf(v)); }
__device__ inline float silu(float v) { return v / (1.f + __expf(-v)); }

// ---------------- weight transpose + cvt: W (L,K,N) -> Wb (L,N,K) bf16
__global__ void wprep(const float* __restrict__ W, __bf16* __restrict__ Wb,
                      int K, int N, int kshift) {
  int l = blockIdx.y;
  int idx = blockIdx.x * 256 + threadIdx.x;
  if (idx >= N * K) return;
  int n = idx >> kshift, k = idx & (K - 1);
  Wb[(size_t)l * N * K + idx] = (__bf16)W[(size_t)l * K * N + (size_t)k * N + n];
}

// ---------------- embed -> split bf16 x
__global__ void embed_kernel(const int* __restrict__ grid,
                             const float* __restrict__ cemb,
                             const float* __restrict__ pemb,
                             __bf16* __restrict__ xh, __bf16* __restrict__ xl) {
  int row = blockIdx.x;
  int c = threadIdx.x;
  int s = row % SEQC;
  int g = grid[row];
  float v = cemb[g * D_MODELC + c] + pemb[s * D_MODELC + c];
  size_t o = (size_t)row * D_MODELC + c;
  __bf16 hh = (__bf16)v;
  xh[o] = hh;
  xl[o] = (__bf16)(v - (float)hh);
}

// ---------------- bf16 MFMA GEMM: C = A(MxK) * W^T(NxK) + bias
// 128x128 tile, 4 waves (2x2), BK=32, single-buffer. XCD supertile swizzle.
// OPERAND-SWAPPED MFMA: D = Wfrag x Afrag -> per lane, reg i holds 4
// consecutive OUTPUT COLS at fixed row -> packed 8B stores (4x fewer
// store instrs than the scalar-per-col epilogue; r16 was store-issue bound).
// MODE 1: bf16 Cb, softplus cols<16 (x-proj).  MODE 2: in-proj split+silu.
// MODE 3: bf16 Cb plain.  GUARD: compile-time col guards (x-proj only).
#define GLDA 44
template<int MODE, bool GUARD>
__global__ __launch_bounds__(256) void gemm_bf16(
    const __bf16* __restrict__ A, const __bf16* __restrict__ W,
    const float* __restrict__ bias,
    __bf16* __restrict__ Cb, __bf16* __restrict__ Cg,
    int M, int N, int K, int nrow, int ncol) {
  __shared__ __attribute__((aligned(16))) __bf16 As[128 * GLDA];
  __shared__ __attribute__((aligned(16))) __bf16 Bs[128 * GLDA];
  int id = blockIdx.x;
  int row, col;
  {
    int fullsup = (nrow >> 3) * 8 * ncol;
    if (id < fullsup) {
      int per = ncol * 8;
      int s = id / per, r = id % per;
      col = r >> 3;
      row = (s << 3) + (r & 7);
    } else {
      int r = id - fullsup;
      int tr = nrow & 7;
      col = r / tr;
      row = (nrow & ~7) + r % tr;
    }
  }
  int tid = threadIdx.x, lane = tid & 63, w = tid >> 6;
  int bm = row * 128, bn = col * 128;
  int wm = (w >> 1) * 64, wn = (w & 1) * 64;
  int lm = lane & 15, kq = lane >> 4;
  bool wactive = !GUARD || (bn + wn < N);

  // acc[wf][af]: wf = W col-fragment (output cols), af = A row-fragment
  floatx4 acc[4][4];
  floatx4 zero = {0.f, 0.f, 0.f, 0.f};
  #pragma unroll
  for (int i = 0; i < 4; ++i)
    #pragma unroll
    for (int j = 0; j < 4; ++j) acc[i][j] = zero;

  int r0 = tid >> 1;          // 0..127
  int kb = (tid & 1) * 16;    // 0 / 16

  for (int k0 = 0; k0 < K; k0 += 32) {
    __syncthreads();
    {
      size_t aoff = (size_t)(bm + r0) * K + k0 + kb;
      *(bf16x8*)&As[r0 * GLDA + kb]     = *(const bf16x8*)&A[aoff];
      *(bf16x8*)&As[r0 * GLDA + kb + 8] = *(const bf16x8*)&A[aoff + 8];
      int nr = bn + r0;
      if (!GUARD || nr < N) {
        size_t boff = (size_t)nr * K + k0 + kb;
        *(bf16x8*)&Bs[r0 * GLDA + kb]     = *(const bf16x8*)&W[boff];
        *(bf16x8*)&Bs[r0 * GLDA + kb + 8] = *(const bf16x8*)&W[boff + 8];
      } else {
        uint4 zu = make_uint4(0, 0, 0, 0);
        *(uint4*)&Bs[r0 * GLDA + kb] = zu;
        *(uint4*)&Bs[r0 * GLDA + kb + 8] = zu;
      }
    }
    __syncthreads();
    if (wactive) {
      bf16x8 fa[4], fb[4];
      #pragma unroll
      for (int af = 0; af < 4; ++af)
        fa[af] = *(const bf16x8*)&As[(wm + af * 16 + lm) * GLDA + kq * 8];
      #pragma unroll
      for (int wf = 0; wf < 4; ++wf)
        fb[wf] = *(const bf16x8*)&Bs[(wn + wf * 16 + lm) * GLDA + kq * 8];
      #pragma unroll
      for (int wf = 0; wf < 4; ++wf)
        #pragma unroll
        for (int af = 0; af < 4; ++af)
          acc[wf][af] = __builtin_amdgcn_mfma_f32_16x16x32_bf16(fb[wf], fa[af], acc[wf][af], 0, 0, 0);
    }
  }

  if (!wactive) return;
  // epilogue: lane holds row = bm+wm+af*16+lm (fixed per af),
  //           cols = bn+wn+wf*16+kq*4 + i  (4 consecutive -> one 8B store)
  #pragma unroll
  for (int wf = 0; wf < 4; ++wf) {
    int colg = bn + wn + wf * 16 + kq * 4;
    if (GUARD && colg >= N) continue;
    float4 bz4 = *(const float4*)&bias[colg];
    float bz[4] = {bz4.x, bz4.y, bz4.z, bz4.w};
    #pragma unroll
    for (int af = 0; af < 4; ++af) {
      int rr = bm + wm + af * 16 + lm;
      bf16x4 pk;
      #pragma unroll
      for (int i = 0; i < 4; ++i) {
        float v = acc[wf][af][i] + bz[i];
        if (MODE == 1) {
          if (colg < 16) v = sp(v);          // group fully <16 or >=16
        } else if (MODE == 2) {
          if (colg >= 512) v = silu(v);
        }
        pk[i] = (__bf16)v;
      }
      if (MODE == 2) {
        if (colg < 512) *(bf16x4*)&Cb[(size_t)rr * 512 + colg] = pk;
        else            *(bf16x4*)&Cg[(size_t)rr * 512 + colg - 512] = pk;
      } else {
        *(bf16x4*)&Cb[(size_t)rr * N + colg] = pk;
      }
    }
  }
}

// ---------------- depthwise causal conv (k=4) + SiLU, sliding window, 4 rows/thread
__global__ __launch_bounds__(256) void conv_silu(
    const __bf16* __restrict__ xs, const float* __restrict__ cw,
    const float* __restrict__ cb, __bf16* __restrict__ xc, int total) {
  int idx = blockIdx.x * 256 + threadIdx.x;   // < R*16
  if (idx >= total) return;
  int d8 = (idx & 63) * 8;
  int g4 = idx >> 6;
  int bt0 = g4 * 4;
  int t0 = bt0 % SEQC;
  const __bf16* base = xs + (size_t)(bt0 - t0) * 512 + d8;  // seq start
  float wv[8][4];
  #pragma unroll
  for (int e = 0; e < 8; ++e) {
    float4 wq = *(const float4*)&cw[(d8 + e) * 4];
    wv[e][0] = wq.x; wv[e][1] = wq.y; wv[e][2] = wq.z; wv[e][3] = wq.w;
  }
  float4 b0 = *(const float4*)&cb[d8];
  float4 b1 = *(const float4*)&cb[d8 + 4];
  float bb[8] = {b0.x, b0.y, b0.z, b0.w, b1.x, b1.y, b1.z, b1.w};
  float xw[7][8];
  #pragma unroll
  for (int j = 0; j < 7; ++j) {
    int ts = t0 - 3 + j;
    if (ts >= 0) {
      bf16x8 v = *(const bf16x8*)&base[(size_t)ts * 512];
      #pragma unroll
      for (int e = 0; e < 8; ++e) xw[j][e] = (float)v[e];
    } else {
      #pragma unroll
      for (int e = 0; e < 8; ++e) xw[j][e] = 0.f;
    }
  }
  #pragma unroll
  for (int i = 0; i < 4; ++i) {
    bf16x8 o;
    #pragma unroll
    for (int e = 0; e < 8; ++e) {
      float acc = bb[e];
      #pragma unroll
      for (int j = 0; j < 4; ++j) acc = fmaf(wv[e][j], xw[i + j][e], acc);
      o[e] = (__bf16)silu(acc);
    }
    *(bf16x8*)&xc[(size_t)(bt0 + i) * 512 + d8] = o;
  }
}

// ---------------- scan phase 1: per-chunk local scan (h=0) -> hend, P (bf16)
__global__ __launch_bounds__(256, 4) void scan_phase1(
    const __bf16* __restrict__ ssm, const float* __restrict__ A_log,
    const __bf16* __restrict__ xc,
    __bf16* __restrict__ hend, __bf16* __restrict__ Pp) {
  __shared__ float sb[SUB * 32];
  int b = blockIdx.x, half = blockIdx.y, c = blockIdx.z;
  int tid = threadIdx.x;
  int dg0 = half * 256;
  int d = dg0 + tid;
  floatx2 a2p[8];
  #pragma unroll
  for (int n = 0; n < 8; ++n) {
    a2p[n][0] = -__expf(A_log[d * 16 + 2 * n]) * LOG2E;
    a2p[n][1] = -__expf(A_log[d * 16 + 2 * n + 1]) * LOG2E;
  }
  floatx2 h2[8], S2[8];
  #pragma unroll
  for (int n = 0; n < 8; ++n) { h2[n] = floatx2{0.f, 0.f}; S2[n] = floatx2{0.f, 0.f}; }
  size_t rowbase = (size_t)b * SEQC + c * CT;

  floatx2 dA[8], BA[8], dB[8], BB[8];
  float xA, xB;
  auto loadt = [&](int ts0, int tt, floatx2* del, floatx2* Bv, float& xv) {
    const floatx2* p = (const floatx2*)&sb[tt * 32];
    #pragma unroll
    for (int n = 0; n < 8; ++n) { del[n] = p[n]; Bv[n] = p[8 + n]; }
    xv = (float)xc[(rowbase + ts0 + tt) * 512 + d];
  };
  auto stept = [&](floatx2* del, floatx2* Bv, float xv) {
    floatx2 xv2 = {xv, xv};
    #pragma unroll
    for (int n = 0; n < 8; ++n) {
      S2[n] += del[n];
      floatx2 t2 = a2p[n] * del[n];
      floatx2 e2;
      e2[0] = EXP2F(t2[0]); e2[1] = EXP2F(t2[1]);
      h2[n] = h2[n] * e2 + xv2 * Bv[n];
    }
  };

  for (int sub = 0; sub < 2; ++sub) {
    int ts0 = sub * SUB;
    __syncthreads();
    for (int i = tid; i < SUB * 8; i += 256) {
      int tt = i >> 3, n4 = (i & 7) * 4;
      bf16x4 v = *(const bf16x4*)&ssm[(rowbase + ts0 + tt) * 32 + n4];
      float4 f = {(float)v[0], (float)v[1], (float)v[2], (float)v[3]};
      *(float4*)&sb[tt * 32 + n4] = f;
    }
    __syncthreads();
    loadt(ts0, 0, dA, BA, xA);
    for (int tt = 0; tt < SUB - 1; tt += 2) {
      loadt(ts0, tt + 1, dB, BB, xB);
      stept(dA, BA, xA);
      if (tt + 2 < SUB) loadt(ts0, tt + 2, dA, BA, xA);
      stept(dB, BB, xB);
    }
    stept(dA, BA, xA);   // SUB odd: last step
  }
  size_t base = ((size_t)(b * NCH + c) * 512 + d) * 16;
  bf16x8 h0, h1, p0, p1;
  #pragma unroll
  for (int n = 0; n < 4; ++n) {
    h0[2 * n] = (__bf16)h2[n][0];     h0[2 * n + 1] = (__bf16)h2[n][1];
    h1[2 * n] = (__bf16)h2[n + 4][0]; h1[2 * n + 1] = (__bf16)h2[n + 4][1];
    p0[2 * n] = (__bf16)EXP2F(a2p[n][0] * S2[n][0]);
    p0[2 * n + 1] = (__bf16)EXP2F(a2p[n][1] * S2[n][1]);
    p1[2 * n] = (__bf16)EXP2F(a2p[n + 4][0] * S2[n + 4][0]);
    p1[2 * n + 1] = (__bf16)EXP2F(a2p[n + 4][1] * S2[n + 4][1]);
  }
  *(bf16x8*)&hend[base] = h0; *(bf16x8*)&hend[base + 8] = h1;
  *(bf16x8*)&Pp[base] = p0;   *(bf16x8*)&Pp[base + 8] = p1;
}

// ---------------- scan phase 2: sequential carry composition (hend -> hin in place)
__global__ __launch_bounds__(64) void scan_combine(
    __bf16* __restrict__ hend, const __bf16* __restrict__ Pp) {
  int b = blockIdx.x;
  int d = blockIdx.y * 64 + threadIdx.x;
  float hp[16] = {};
  for (int c = 0; c < NCH; ++c) {
    size_t base = ((size_t)(b * NCH + c) * 512 + d) * 16;
    bf16x8 he0 = *(const bf16x8*)&hend[base];
    bf16x8 he1 = *(const bf16x8*)&hend[base + 8];
    bf16x8 pp0 = *(const bf16x8*)&Pp[base];
    bf16x8 pp1 = *(const bf16x8*)&Pp[base + 8];
    bf16x8 o0, o1;
    #pragma unroll
    for (int n = 0; n < 8; ++n) {
      o0[n] = (__bf16)hp[n]; o1[n] = (__bf16)hp[n + 8];
      hp[n]     = fmaf((float)pp0[n], hp[n],     (float)he0[n]);
      hp[n + 8] = fmaf((float)pp1[n], hp[n + 8], (float)he1[n]);
    }
    *(bf16x8*)&hend[base] = o0; *(bf16x8*)&hend[base + 8] = o1;
  }
}

// ---------------- scan phase 3: local scan with carry, y, gate -> yc bf16
__global__ __launch_bounds__(256, 4) void scan_phase3(
    const __bf16* __restrict__ ssm, const float* __restrict__ A_log,
    const float* __restrict__ Dp, const __bf16* __restrict__ xc,
    const __bf16* __restrict__ gate, const __bf16* __restrict__ hin,
    __bf16* __restrict__ yc) {
  __shared__ float sb[SUB * 32];
  int b = blockIdx.x, half = blockIdx.y, c = blockIdx.z;
  int tid = threadIdx.x;
  int dg0 = half * 256;
  int d = dg0 + tid;
  floatx2 a2p[8];
  #pragma unroll
  for (int n = 0; n < 8; ++n) {
    a2p[n][0] = -__expf(A_log[d * 16 + 2 * n]) * LOG2E;
    a2p[n][1] = -__expf(A_log[d * 16 + 2 * n + 1]) * LOG2E;
  }
  float Dv = Dp[d];
  floatx2 h2[8];
  {
    size_t base = ((size_t)(b * NCH + c) * 512 + d) * 16;
    bf16x8 h0 = *(const bf16x8*)&hin[base];
    bf16x8 h1 = *(const bf16x8*)&hin[base + 8];
    #pragma unroll
    for (int n = 0; n < 4; ++n) {
      h2[n][0] = (float)h0[2 * n];     h2[n][1] = (float)h0[2 * n + 1];
      h2[n + 4][0] = (float)h1[2 * n]; h2[n + 4][1] = (float)h1[2 * n + 1];
    }
  }
  size_t rowbase = (size_t)b * SEQC + c * CT;

  floatx2 dA[8], BA[8], dB[8], BB[8];
  float xA, xB;
  auto loadt = [&](int ts0, int tt, floatx2* del, floatx2* Bv, float& xv) {
    const floatx2* p = (const floatx2*)&sb[tt * 32];
    #pragma unroll
    for (int n = 0; n < 8; ++n) { del[n] = p[n]; Bv[n] = p[8 + n]; }
    xv = (float)xc[(rowbase + ts0 + tt) * 512 + d];
  };
  auto stept = [&](int ts0, int tt, floatx2* del, floatx2* Bv, float xv) {
    floatx2 xv2 = {xv, xv};
    floatx2 yq0 = {0.f, 0.f}, yq1 = {0.f, 0.f}, yq2 = {0.f, 0.f}, yq3 = {0.f, 0.f};
    #pragma unroll
    for (int n = 0; n < 8; ++n) {
      floatx2 t2 = a2p[n] * del[n];
      floatx2 e2;
      e2[0] = EXP2F(t2[0]); e2[1] = EXP2F(t2[1]);
      h2[n] = h2[n] * e2 + xv2 * Bv[n];
      if ((n & 3) == 0) yq0 = h2[n] * Bv[n] + yq0;
      else if ((n & 3) == 1) yq1 = h2[n] * Bv[n] + yq1;
      else if ((n & 3) == 2) yq2 = h2[n] * Bv[n] + yq2;
      else yq3 = h2[n] * Bv[n] + yq3;
    }
    float ysum = ((yq0[0] + yq0[1]) + (yq1[0] + yq1[1])) +
                 ((yq2[0] + yq2[1]) + (yq3[0] + yq3[1]));
    float y = fmaf(Dv, xv, ysum);
    size_t o = (rowbase + ts0 + tt) * 512 + d;
    float g = (float)gate[o];
    yc[o] = (__bf16)(y * g);
  };

  for (int sub = 0; sub < 2; ++sub) {
    int ts0 = sub * SUB;
    __syncthreads();
    for (int i = tid; i < SUB * 8; i += 256) {
      int tt = i >> 3, n4 = (i & 7) * 4;
      bf16x4 v = *(const bf16x4*)&ssm[(rowbase + ts0 + tt) * 32 + n4];
      float4 f = {(float)v[0], (float)v[1], (float)v[2], (float)v[3]};
      *(float4*)&sb[tt * 32 + n4] = f;
    }
    __syncthreads();
    loadt(ts0, 0, dA, BA, xA);
    for (int tt = 0; tt < SUB - 1; tt += 2) {
      loadt(ts0, tt + 1, dB, BB, xB);
      stept(ts0, tt, dA, BA, xA);
      if (tt + 2 < SUB) loadt(ts0, tt + 2, dA, BA, xA);
      stept(ts0, tt + 1, dB, BB, xB);
    }
    stept(ts0, SUB - 1, dA, BA, xA);   // SUB odd: last step
  }
}

// ---------------- x = LayerNorm(reconstruct(xh,xl) + ob_bf16), re-split; 4 rows/block
__global__ __launch_bounds__(256) void add_ln(
    __bf16* __restrict__ xh, __bf16* __restrict__ xl,
    const __bf16* __restrict__ ob,
    const float* __restrict__ g, const float* __restrict__ bb) {
  int lane = threadIdx.x & 63;
  size_t base = ((size_t)blockIdx.x * 4 + (threadIdx.x >> 6)) * 256;
  bf16x4 h4 = *(const bf16x4*)&xh[base + lane * 4];
  bf16x4 l4 = *(const bf16x4*)&xl[base + lane * 4];
  bf16x4 o4 = *(const bf16x4*)&ob[base + lane * 4];
  float v[4];
  #pragma unroll
  for (int i = 0; i < 4; ++i) v[i] = (float)h4[i] + (float)l4[i] + (float)o4[i];
  float s = v[0] + v[1] + v[2] + v[3];
  #pragma unroll
  for (int off = 32; off > 0; off >>= 1) s += __shfl_down(s, off);
  float mu = __shfl(s, 0) * (1.f / 256.f);
  float var = 0.f;
  #pragma unroll
  for (int i = 0; i < 4; ++i) { float dd = v[i] - mu; var = fmaf(dd, dd, var); }
  #pragma unroll
  for (int off = 32; off > 0; off >>= 1) var += __shfl_down(var, off);
  float r = rsqrtf(__shfl(var, 0) * (1.f / 256.f) + LN_EPSF);
  float4 gv = *(const float4*)&g[lane * 4];
  float4 bv = *(const float4*)&bb[lane * 4];
  float gg[4] = {gv.x, gv.y, gv.z, gv.w};
  float bbv[4] = {bv.x, bv.y, bv.z, bv.w};
  bf16x4 hq, lq;
  #pragma unroll
  for (int i = 0; i < 4; ++i) {
    float o = (v[i] - mu) * r * gg[i] + bbv[i];
    __bf16 hh = (__bf16)o;
    hq[i] = hh;
    lq[i] = (__bf16)(o - (float)hh);
  }
  *(bf16x4*)&xh[base + lane * 4] = hq;
  *(bf16x4*)&xl[base + lane * 4] = lq;
}

// ---------------- fin[b][256] = reconstruct(x) at t=899
__global__ void extract_final(const __bf16* __restrict__ xh,
                              const __bf16* __restrict__ xl,
                              float* __restrict__ fin) {
  int b = blockIdx.x;
  int c = threadIdx.x;
  size_t o = ((size_t)b * SEQC + (SEQC - 1)) * D_MODELC + c;
  fin[(size_t)b * 256 + c] = (float)xh[o] + (float)xl[o];
}

// ---------------- final heads
__global__ __launch_bounds__(128) void heads_kernel(
    const float* __restrict__ fin,
    const float* __restrict__ cnt1_w, const float* __restrict__ cnt1_b,
    const float* __restrict__ cnt2_w, const float* __restrict__ cnt2_b,
    const float* __restrict__ col1_w, const float* __restrict__ col1_b,
    const float* __restrict__ col2_w, const float* __restrict__ col2_b,
    float* __restrict__ out) {
  int b = blockIdx.x;
  int tid = threadIdx.x;
  __shared__ float f[256];
  __shared__ float hc[128];
  __shared__ float hl[128];
  f[tid] = fin[b * 256 + tid];
  f[tid + 128] = fin[b * 256 + tid + 128];
  __syncthreads();
  float s1 = cnt1_b[tid], s2 = col1_b[tid];
  for (int c = 0; c < 256; ++c) {
    float v = f[c];
    s1 = fmaf(v, cnt1_w[c * 128 + tid], s1);
    s2 = fmaf(v, col1_w[c * 128 + tid], s2);
  }
  hc[tid] = fmaxf(s1, 0.f);
  hl[tid] = fmaxf(s2, 0.f);
  __syncthreads();
  if (tid == 0) {
    float t = cnt2_b[0];
    for (int j = 0; j < 128; ++j) t = fmaf(hc[j], cnt2_w[j], t);
    out[b] = fmaxf(t, 0.f);
  }
  if (tid < 10) {
    float t = col2_b[tid];
    for (int j = 0; j < 128; ++j) t = fmaf(hl[j], col2_w[j * 10 + tid], t);
    out[64 + b * 10 + tid] = fmaxf(t, 0.f);
  }
}

extern "C" void kernel_launch(void* const* d_in, const int* in_sizes, int n_in,
                              void* d_out, int out_size, void* d_ws, size_t ws_size,
                              hipStream_t stream) {
  const int*   grid   = (const int*)d_in[0];
  const float* cemb   = (const float*)d_in[1];
  const float* pemb   = (const float*)d_in[2];
  const float* in_w   = (const float*)d_in[3];
  const float* in_b   = (const float*)d_in[4];
  const float* conv_w = (const float*)d_in[5];
  const float* conv_b = (const float*)d_in[6];
  const float* xproj_w= (const float*)d_in[7];
  const float* xproj_b= (const float*)d_in[8];
  const float* A_log  = (const float*)d_in[9];
  const float* Dp     = (const float*)d_in[10];
  const float* out_w  = (const float*)d_in[11];
  const float* out_b  = (const float*)d_in[12];
  const float* ln_g   = (const float*)d_in[13];
  const float* ln_b   = (const float*)d_in[14];
  const float* cnt1_w = (const float*)d_in[15];
  const float* cnt1_b = (const float*)d_in[16];
  const float* cnt2_w = (const float*)d_in[17];
  const float* cnt2_b = (const float*)d_in[18];
  const float* col1_w = (const float*)d_in[19];
  const float* col1_b = (const float*)d_in[20];
  const float* col2_w = (const float*)d_in[21];
  const float* col2_b = (const float*)d_in[22];

  const int R = BATCHC * SEQC;  // 57600
  float* ws = (float*)d_ws;
  size_t off = 0;
  auto alloc = [&](size_t fl) { float* p = ws + off; off += (fl + 63) & ~(size_t)63; return p; };

  float*  fin   = alloc((size_t)BATCHC * 256);
  __bf16* wi    = (__bf16*)alloc((size_t)N_LAYERSC * 1024 * 256 / 2);
  __bf16* wx    = (__bf16*)alloc((size_t)N_LAYERSC * 32 * 512 / 2);
  __bf16* wo    = (__bf16*)alloc((size_t)N_LAYERSC * 256 * 512 / 2);
  __bf16* xh    = (__bf16*)alloc((size_t)R * 256 / 2);
  __bf16* xl    = (__bf16*)alloc((size_t)R * 256 / 2);
  __bf16* xsyc  = (__bf16*)alloc((size_t)R * 512 / 2);   // xs then yc
  float*  gateob= alloc((size_t)R * 512 / 2);            // gate bf16, then ob bf16
  __bf16* xc    = (__bf16*)alloc((size_t)R * 512 / 2);
  __bf16* ssm   = (__bf16*)alloc((size_t)R * 32 / 2);
  __bf16* hend  = (__bf16*)alloc((size_t)BATCHC * NCH * 512 * 16 / 2);
  __bf16* Pp    = (__bf16*)alloc((size_t)BATCHC * NCH * 512 * 16 / 2);
  __bf16* gate  = (__bf16*)gateob;
  __bf16* obb   = (__bf16*)gateob;   // out-proj result (gate dead after phase3)

  // weight prep (once per call)
  wprep<<<dim3(1024, N_LAYERSC), 256, 0, stream>>>(in_w, wi, 256, 1024, 8);
  wprep<<<dim3(64, N_LAYERSC), 256, 0, stream>>>(xproj_w, wx, 512, 32, 9);
  wprep<<<dim3(512, N_LAYERSC), 256, 0, stream>>>(out_w, wo, 512, 256, 9);

  embed_kernel<<<R, 256, 0, stream>>>(grid, cemb, pemb, xh, xl);

  const int NROW = R / 128;   // 450
  for (int l = 0; l < N_LAYERSC; ++l) {
    // in-proj: xs (bf16) + gate = silu(res) (bf16); 1D swizzled grid
    gemm_bf16<2, false><<<NROW * 8, 256, 0, stream>>>(
        xh, wi + (size_t)l * 1024 * 256, in_b + l * 1024,
        xsyc, gate, R, 1024, 256, NROW, 8);
    conv_silu<<<(R * 16 + 255) / 256, 256, 0, stream>>>(
        xsyc, conv_w + (size_t)l * 512 * 4, conv_b + l * 512, xc, R * 16);
    // x-proj: ssm bf16, softplus fused on delta cols (guarded, 1 col tile)
    gemm_bf16<1, true><<<NROW, 256, 0, stream>>>(
        xc, wx + (size_t)l * 32 * 512, xproj_b + l * 32,
        ssm, nullptr, R, 32, 512, NROW, 1);
    // phase1: chunk NCH-1 skipped (output unused by combine)
    scan_phase1<<<dim3(BATCHC, 2, NCH - 1), 256, 0, stream>>>(
        ssm, A_log + (size_t)l * 512 * 16, xc, hend, Pp);
    scan_combine<<<dim3(BATCHC, 8), 64, 0, stream>>>(hend, Pp);
    scan_phase3<<<dim3(BATCHC, 2, NCH), 256, 0, stream>>>(
        ssm, A_log + (size_t)l * 512 * 16, Dp + l * 512, xc, gate, hend, xsyc);
    // out-proj: ob bf16 (overwrites gate region — gate dead after phase3)
    gemm_bf16<3, false><<<NROW * 2, 256, 0, stream>>>(
        xsyc, wo + (size_t)l * 256 * 512, out_b + l * 256,
        obb, nullptr, R, 256, 512, NROW, 2);
    add_ln<<<R / 4, 256, 0, stream>>>(xh, xl, obb, ln_g, ln_b);
  }

  extract_final<<<BATCHC, 256, 0, stream>>>(xh, xl, fin);
  heads_kernel<<<BATCHC, 128, 0, stream>>>(
      fin, cnt1_w, cnt1_b, cnt2_w, cnt2_b, col1_w, col1_b, col2_w, col2_b,
      (float*)d_out);
}